// Round 11
// baseline (206.947 us; speedup 1.0000x reference)
//
#include <hip/hip_runtime.h>

#define Bn 32
#define Nn 24564
#define MAXB 200
#define NBIN 2048
#define CH 2048
#define NCHK 4
#define INVK 0xFFFFFFFFu

typedef unsigned long long u64;
typedef unsigned int u32;

// -------- accurate double exp (rel err ~6e-15) -- bit-stable since R2 --------
__device__ inline double fast_exp_d(double x) {
  const double LOG2E = 1.4426950408889634074;
  const double LN2   = 0.69314718055994530942;
  double t = x * LOG2E;
  double fi = floor(t + 0.5);
  double f = (t - fi) * LN2;
  double p = 2.505210838544172e-8;
  p = p * f + 2.755731922398589e-7;
  p = p * f + 2.7557319223985893e-6;
  p = p * f + 2.48015873015873e-5;
  p = p * f + 1.984126984126984e-4;
  p = p * f + 1.3888888888888889e-3;
  p = p * f + 8.333333333333333e-3;
  p = p * f + 4.1666666666666664e-2;
  p = p * f + 1.6666666666666666e-1;
  p = p * f + 0.5;
  p = p * f + 1.0;
  p = p * f + 1.0;
  long long e = (long long)fi;
  return p * __longlong_as_double((e + 1023LL) << 52);
}

__device__ inline double clip01(double v) {
  return v < 0.0 ? 0.0 : (v > 1.0 ? 1.0 : v);
}

// ============================================================
// v1: f32 scoring -> u32 key per anchor (proven ~54us, 78% HBM)
// ============================================================
__global__ __launch_bounds__(256) void v1_score(const float* __restrict__ logits,
                                                u32* __restrict__ keyA) {
  __shared__ float lds[64 * 85];
  const int tid = threadIdx.x;
  const int bx = blockIdx.x;
  const int b = bx / 384;
  const int n0 = (bx % 384) << 6;
  int cnt = Nn - n0;
  cnt = cnt > 64 ? 64 : cnt;
  const int nf4 = (cnt * 85) >> 2;
  const float4* src = reinterpret_cast<const float4*>(logits + ((size_t)b * Nn + n0) * 85);
  float4* dst = reinterpret_cast<float4*>(lds);
  for (int i = tid; i < nf4; i += 256) dst[i] = src[i];
  __syncthreads();

  const int g = tid >> 2;
  const int s = tid & 3;
  if (g < cnt) {
    const float* row = lds + g * 85;
    float mx = -1e30f; int ai = 1000;
    for (int c = s; c < 81; c += 4) {
      float v = row[4 + c];
      if (v > mx) { mx = v; ai = c; }
    }
    #pragma unroll
    for (int d = 1; d <= 2; d <<= 1) {
      float om = __shfl_xor(mx, d);
      int oi = __shfl_xor(ai, d);
      if (om > mx || (om == mx && oi < ai)) { mx = om; ai = oi; }
    }
    float sum = 0.f;
    for (int c = s; c < 81; c += 4) sum += __expf(row[4 + c] - mx);
    sum += __shfl_xor(sum, 1);
    sum += __shfl_xor(sum, 2);
    if (s == 0) {
      float sc = 1.0f / sum;
      u32 kv = INVK;
      if (ai != 0 && sc >= 0.00985f) kv = ~__float_as_uint(sc);  // margin; exact recheck later
      keyA[(size_t)b * Nn + n0 + g] = kv;
    }
  }
}

// ============================================================
// v2: partial histograms, 8 blocks/image, NON-atomic global writes
// ============================================================
__global__ __launch_bounds__(256) void v2_hist(const u32* __restrict__ keyA,
                                               int* __restrict__ histP) {
  __shared__ int hl[NBIN];
  const int tid = threadIdx.x;
  const int bx = blockIdx.x;
  const int b = bx >> 3;
  const int p = bx & 7;
  const int sl = p * 3072;
  for (int i = tid; i < NBIN; i += 256) hl[i] = 0;
  __syncthreads();
  const u32* kb = keyA + (size_t)b * Nn;
  for (int k = 0; k < 12; ++k) {
    int i = sl + k * 256 + tid;
    if (i < Nn) {
      u32 kv = kb[i];
      u32 bin = (kv - 0xC0000000u) >> 15;
      if (bin < NBIN) atomicAdd(&hl[bin], 1);
    }
  }
  __syncthreads();
  int* dst = histP + ((size_t)(b << 3) + p) * NBIN;
  for (int i = tid; i < NBIN; i += 256) dst[i] = hl[i];
}

// ============================================================
// v3: per-image MEGA-kernel, all-LDS:
// hist-sum -> cumsum -> boundaries -> per chunk (lazy): compact ->
// inline exact f64 rescore (boxes/cls straight to LDS) ->
// payload bitonic sort -> multi-wave NMS -> outputs.
// ============================================================
__global__ __launch_bounds__(1024) void v3_selnms(const int* __restrict__ histP,
                                                  const u32* __restrict__ keyA,
                                                  const float* __restrict__ logits,
                                                  const float* __restrict__ anchors,
                                                  float* __restrict__ out) {
  __shared__ int hist[NBIN];          // inclusive cumsum
  __shared__ int chunkIdL[NBIN];
  __shared__ int wsum[16];
  __shared__ int sBinHi, sCnt, sS;
  __shared__ u64 ek[CH];              // 16 KB sort keys
  __shared__ u32 slotP[CH];           //  8 KB payload (slot index)
  __shared__ int clist[CH];           //  8 KB slot -> anchor n
  __shared__ double cbox[CH][4];      // 64 KB slot -> exact f64 box
  __shared__ unsigned char clsL[CH];  //  2 KB slot -> class
  __shared__ u64 awv[16];
  __shared__ u64 killm[64];
  __shared__ double selBox[MAXB][4];
  __shared__ double selArea[MAXB];
  __shared__ float selScore[MAXB];
  __shared__ float selCls[MAXB];

  const int b = blockIdx.x;
  const int tid = threadIdx.x;
  const int lane = tid & 63, wid = tid >> 6;
  const u32* kb = keyA + (size_t)b * Nn;
  const double THR = 0.45;

  // --- sum partial hists (regs) ---
  int h0 = 0, h1 = 0;
  #pragma unroll
  for (int p = 0; p < 8; ++p) {
    const int* src = histP + ((size_t)(b << 3) + p) * NBIN;
    h0 += src[2 * tid];
    h1 += src[2 * tid + 1];
  }
  chunkIdL[2 * tid] = 255;
  chunkIdL[2 * tid + 1] = 255;
  if (tid == 0) sS = 0;

  // --- inclusive prefix scan (proven R6 code) ---
  int v = h0 + h1;
  int iv = v;
  #pragma unroll
  for (int d = 1; d < 64; d <<= 1) {
    int t = __shfl_up(iv, d);
    if (lane >= d) iv += t;
  }
  if (lane == 63) wsum[wid] = iv;
  __syncthreads();
  if (tid < 16) {
    int w = wsum[tid];
    #pragma unroll
    for (int d = 1; d < 16; d <<= 1) {
      int t = __shfl_up(w, d);
      if ((int)tid >= d) w += t;
    }
    wsum[tid] = w;
  }
  __syncthreads();
  int excl = iv - v + (wid > 0 ? wsum[wid - 1] : 0);
  hist[2 * tid] = excl + h0;
  hist[2 * tid + 1] = excl + h0 + h1;
  __syncthreads();

  // --- chunk boundaries (proven R8 loop) ---
  {
    int binLo = -1, cumBase = 0;
    for (int c = 0; c < NCHK; ++c) {
      if (tid == 0) sBinHi = binLo;
      __syncthreads();
      const int limit = cumBase + CH;
      int loc = -1;
      if (hist[2 * tid] <= limit) loc = 2 * tid;
      if (hist[2 * tid + 1] <= limit) loc = 2 * tid + 1;
      if (loc > binLo) atomicMax(&sBinHi, loc);
      __syncthreads();
      int binHi = sBinHi;
      if (binHi == binLo) binHi = binLo + 1;   // oversized-single-bin fallback
      if (2 * tid > binLo && 2 * tid <= binHi) chunkIdL[2 * tid] = c;
      if (2 * tid + 1 > binLo && 2 * tid + 1 <= binHi) chunkIdL[2 * tid + 1] = c;
      cumBase = hist[(binHi < NBIN ? binHi : NBIN - 1)];
      binLo = binHi;
      __syncthreads();
    }
  }

  // --- lazy chunk loop ---
  for (int c = 0; c < NCHK; ++c) {
    if (sS >= MAXB) break;
    if (tid == 0) sCnt = 0;
    for (int i = tid; i < CH; i += 1024) { ek[i] = ~0ULL; slotP[i] = (u32)i; }
    __syncthreads();

    // compact chunk c (LDS counter, wave-aggregated)
    for (int i0 = 0; i0 < Nn; i0 += 1024) {
      int i = i0 + tid;
      bool pred = false;
      if (i < Nn) {
        u32 kv = kb[i];
        u32 bin = (kv - 0xC0000000u) >> 15;
        pred = (bin < NBIN) && (chunkIdL[bin] == c);
      }
      u64 m = __ballot(pred);
      if (m) {
        int base = 0;
        if (lane == 0) base = atomicAdd(&sCnt, (int)__popcll(m));
        base = __shfl(base, 0);
        if (pred) {
          int off = (int)__popcll(m & ((1ULL << lane) - 1ULL));
          int p = base + off;
          if (p < CH) clist[p] = i;
        }
      }
    }
    __syncthreads();
    int cnt = sCnt; cnt = cnt > CH ? CH : cnt;
    if (cnt == 0) break;

    // inline exact f64 rescore -> ek / cbox / clsL (summation order proven R2)
    {
      const int g = tid >> 2, s4 = tid & 3;
      #pragma unroll 1
      for (int pass = 0; pass < CH / 256; ++pass) {
        int slot = pass * 256 + g;
        if (slot < cnt) {
          const int n = clist[slot];
          const float* row = logits + ((size_t)b * Nn + n) * 85;
          float rv[21];
          float mx = -1e30f; int ai = 1000;
          #pragma unroll
          for (int q = 0; q < 21; ++q) {
            int cc = s4 + 4 * q;
            float vv = (cc < 81) ? row[4 + cc] : -1e30f;
            rv[q] = vv;
            if (cc < 81 && vv > mx) { mx = vv; ai = cc; }
          }
          #pragma unroll
          for (int d = 1; d <= 2; d <<= 1) {
            float om = __shfl_xor(mx, d);
            int oi = __shfl_xor(ai, d);
            if (om > mx || (om == mx && oi < ai)) { mx = om; ai = oi; }
          }
          double sum = 0.0;
          #pragma unroll
          for (int q = 0; q < 21; ++q) {
            if (s4 + 4 * q < 81) sum += fast_exp_d((double)rv[q] - (double)mx);
          }
          sum += __shfl_xor(sum, 1);
          sum += __shfl_xor(sum, 2);
          if (s4 == 0) {
            u64 K = ~0ULL;
            double score = 1.0 / sum;
            if (ai != 0 && score >= 0.01) {
              float4 a4 = reinterpret_cast<const float4*>(anchors)[n];
              double ax1 = a4.x, ay1 = a4.y, ax2 = a4.z, ay2 = a4.w;
              double cx = (ax2 + ax1) * 0.5, cy = (ay2 + ay1) * 0.5;
              double ww = ax2 - ax1, hh = ay2 - ay1;
              double ctrx = (double)row[0] * ww + cx;
              double ctry = (double)row[1] * hh + cy;
              double szx = fast_exp_d((double)row[2]) * ww;
              double szy = fast_exp_d((double)row[3]) * hh;
              cbox[slot][0] = clip01(ctrx - szx * 0.5);
              cbox[slot][1] = clip01(ctry - szy * 0.5);
              cbox[slot][2] = clip01(ctrx + szx * 0.5);
              cbox[slot][3] = clip01(ctry + szy * 0.5);
              clsL[slot] = (unsigned char)ai;
              u64 sb2 = (u64)__double_as_longlong(score);
              u64 e4 = (sb2 >> 52) - 1015ULL;
              u64 mant45 = (sb2 & ((1ULL << 52) - 1)) >> 7;
              u64 flip = (~((e4 << 45) | mant45)) & ((1ULL << 49) - 1);
              K = (flip << 15) | (u64)n;
            }
            ek[slot] = K;
          }
        }
      }
    }
    __syncthreads();

    // payload bitonic sort (key + slot), ascending, first P2 elements
    int P2 = 64;
    while (P2 < cnt) P2 <<= 1;
    for (int k = 2; k <= P2; k <<= 1) {
      for (int j = k >> 1; j >= 1; j >>= 1) {
        if (tid < (P2 >> 1)) {
          int l = ((tid & ~(j - 1)) << 1) | (tid & (j - 1));
          int r = l | j;
          bool up = ((l & k) == 0);
          u64 a = ek[l], bv = ek[r];
          if ((a > bv) == up) {
            ek[l] = bv; ek[r] = a;
            u32 t = slotP[l]; slotP[l] = slotP[r]; slotP[r] = t;
          }
        }
        __syncthreads();
      }
    }

    // ---- multi-wave NMS (boxes read straight from LDS) ----
    int pos = 0;
    for (;;) {
      int S = sS;
      if (S >= MAXB || pos >= CH) break;
      u64 K = ek[pos + lane];
      bool valid = (K != ~0ULL);
      if (!__any(valid)) break;
      int slt = (int)slotP[pos + lane];
      double cx1 = valid ? cbox[slt][0] : 0.0;
      double cy1 = valid ? cbox[slt][1] : 0.0;
      double cx2 = valid ? cbox[slt][2] : 0.0;
      double cy2 = valid ? cbox[slt][3] : 0.0;
      double carea = (cx2 - cx1) * (cy2 - cy1);

      // phase 1: vs committed selections (wave wid handles slice)
      bool aliveL = true;
      for (int k = wid; k < S; k += 16) {
        double ltx = fmax(selBox[k][0], cx1), lty = fmax(selBox[k][1], cy1);
        double rbx = fmin(selBox[k][2], cx2), rby = fmin(selBox[k][3], cy2);
        double w = rbx - ltx; w = w < 0 ? 0 : w;
        double h = rby - lty; h = h < 0 ? 0 : h;
        double inter = w * h;
        double denom = selArea[k] + carea - inter + 1e-9;
        if (inter > THR * denom) aliveL = false;
      }
      u64 aw = __ballot(aliveL);
      if (lane == 0) awv[wid] = aw;

      // phase 1.5: intra-batch kill-masks (wave wid owns j = 4*wid..4*wid+3)
      #pragma unroll
      for (int q = 0; q < 4; ++q) {
        int j = (wid << 2) | q;
        u64 Kj = ek[pos + j];
        int sj = (int)slotP[pos + j];
        bool jv = (Kj != ~0ULL);
        double jx1 = jv ? cbox[sj][0] : 0.0;
        double jy1 = jv ? cbox[sj][1] : 0.0;
        double jx2 = jv ? cbox[sj][2] : 0.0;
        double jy2 = jv ? cbox[sj][3] : 0.0;
        double jar = (jx2 - jx1) * (jy2 - jy1);
        double ltx = fmax(jx1, cx1), lty = fmax(jy1, cy1);
        double rbx = fmin(jx2, cx2), rby = fmin(jy2, cy2);
        double w = rbx - ltx; w = w < 0 ? 0 : w;
        double h = rby - lty; h = h < 0 ? 0 : h;
        double inter = w * h;
        double denom = jar + carea - inter + 1e-9;
        u64 km = __ballot(inter > THR * denom);
        if (lane == 0) killm[j] = km;
      }
      __syncthreads();

      // phase 2: wave 0, pure mask propagation (decisions bit-identical)
      if (tid < 64) {
        u64 alive = __ballot(valid);
        #pragma unroll
        for (int w = 0; w < 16; ++w) alive &= awv[w];
        u64 m = alive;
        int Sl = S;
        while (m != 0 && Sl < MAXB) {
          int j = __ffsll((unsigned long long)m) - 1;
          if (lane == 0) {
            u64 Kj = ek[pos + j];
            int sj = (int)slotP[pos + j];
            double jx1 = cbox[sj][0], jy1 = cbox[sj][1];
            double jx2 = cbox[sj][2], jy2 = cbox[sj][3];
            u64 key49 = (~(Kj >> 15)) & ((1ULL << 49) - 1);
            u64 e = (key49 >> 45) + 1015ULL;
            u64 mant = (key49 & ((1ULL << 45) - 1)) << 7;
            selBox[Sl][0] = jx1; selBox[Sl][1] = jy1;
            selBox[Sl][2] = jx2; selBox[Sl][3] = jy2;
            selArea[Sl] = (jx2 - jx1) * (jy2 - jy1);
            selScore[Sl] = (float)__longlong_as_double((long long)((e << 52) | mant));
            selCls[Sl] = (float)clsL[sj];
          }
          Sl++;
          m &= ~(1ULL << j);
          m &= ~killm[j];
        }
        if (lane == 0) sS = Sl;
      }
      __syncthreads();
      pos += 64;
    }
    __syncthreads();
  }

  // --- outputs (whole buffer read as f32 by harness) ---
  const int S = sS;
  float* det_boxes = out;
  float* det_classes = out + Bn * MAXB * 4;
  float* det_scores = out + Bn * MAXB * 4 + Bn * MAXB;
  float* det_num = out + Bn * MAXB * 4 + 2 * Bn * MAXB;
  for (int k = tid; k < MAXB; k += 1024) {
    int o = b * MAXB + k;
    if (k < S) {
      det_boxes[o * 4 + 0] = (float)selBox[k][0];
      det_boxes[o * 4 + 1] = (float)selBox[k][1];
      det_boxes[o * 4 + 2] = (float)selBox[k][2];
      det_boxes[o * 4 + 3] = (float)selBox[k][3];
      det_classes[o] = selCls[k];
      det_scores[o] = selScore[k];
    } else {
      det_boxes[o * 4 + 0] = 0.f; det_boxes[o * 4 + 1] = 0.f;
      det_boxes[o * 4 + 2] = 0.f; det_boxes[o * 4 + 3] = 0.f;
      det_classes[o] = 0.f;
      det_scores[o] = 0.f;
    }
  }
  if (tid == 0) det_num[b] = (float)S;
}

// ============================================================
extern "C" void kernel_launch(void* const* d_in, const int* in_sizes, int n_in,
                              void* d_out, int out_size, void* d_ws, size_t ws_size,
                              hipStream_t stream) {
  const float* logits = (const float*)d_in[0];
  const float* anchors = (const float*)d_in[1];
  float* out = (float*)d_out;
  char* ws = (char*)d_ws;

  // ws: keyA u32[B*Nn] | histP int[B*8*NBIN]
  u32* keyA  = (u32*)ws;
  int* histP = (int*)(ws + (size_t)Bn * Nn * sizeof(u32));

  v1_score <<<dim3(Bn * 384), dim3(256),  0, stream>>>(logits, keyA);
  v2_hist  <<<dim3(Bn * 8),   dim3(256),  0, stream>>>(keyA, histP);
  v3_selnms<<<dim3(Bn),       dim3(1024), 0, stream>>>(histP, keyA, logits, anchors, out);
}

// Round 12
// 174.738 us; speedup vs baseline: 1.1843x; 1.1843x over previous
//
#include <hip/hip_runtime.h>

#define Bn 32
#define Nn 24564
#define MAXB 200
#define NBIN 2048
#define CH 2048
#define NCHK 4
#define CHK_PRE 2
#define CHTOT (NCHK * CH)
#define CHPRE (CHK_PRE * CH)
#define INVK 0xFFFFFFFFu

typedef unsigned long long u64;
typedef unsigned int u32;

// -------- accurate double exp (rel err ~6e-15) -- bit-stable since R2 --------
__device__ inline double fast_exp_d(double x) {
  const double LOG2E = 1.4426950408889634074;
  const double LN2   = 0.69314718055994530942;
  double t = x * LOG2E;
  double fi = floor(t + 0.5);
  double f = (t - fi) * LN2;
  double p = 2.505210838544172e-8;
  p = p * f + 2.755731922398589e-7;
  p = p * f + 2.7557319223985893e-6;
  p = p * f + 2.48015873015873e-5;
  p = p * f + 1.984126984126984e-4;
  p = p * f + 1.3888888888888889e-3;
  p = p * f + 8.333333333333333e-3;
  p = p * f + 4.1666666666666664e-2;
  p = p * f + 1.6666666666666666e-1;
  p = p * f + 0.5;
  p = p * f + 1.0;
  p = p * f + 1.0;
  long long e = (long long)fi;
  return p * __longlong_as_double((e + 1023LL) << 52);
}

__device__ inline double clip01(double v) {
  return v < 0.0 ? 0.0 : (v > 1.0 ? 1.0 : v);
}

// ============================================================
// w1: f32 scoring -> u32 key per anchor (proven ~54us, 78% HBM)
// ============================================================
__global__ __launch_bounds__(256) void w1_score(const float* __restrict__ logits,
                                                u32* __restrict__ keyA) {
  __shared__ float lds[64 * 85];
  const int tid = threadIdx.x;
  const int bx = blockIdx.x;
  const int b = bx / 384;
  const int n0 = (bx % 384) << 6;
  int cnt = Nn - n0;
  cnt = cnt > 64 ? 64 : cnt;
  const int nf4 = (cnt * 85) >> 2;
  const float4* src = reinterpret_cast<const float4*>(logits + ((size_t)b * Nn + n0) * 85);
  float4* dst = reinterpret_cast<float4*>(lds);
  for (int i = tid; i < nf4; i += 256) dst[i] = src[i];
  __syncthreads();

  const int g = tid >> 2;
  const int s = tid & 3;
  if (g < cnt) {
    const float* row = lds + g * 85;
    float mx = -1e30f; int ai = 1000;
    for (int c = s; c < 81; c += 4) {
      float v = row[4 + c];
      if (v > mx) { mx = v; ai = c; }
    }
    #pragma unroll
    for (int d = 1; d <= 2; d <<= 1) {
      float om = __shfl_xor(mx, d);
      int oi = __shfl_xor(ai, d);
      if (om > mx || (om == mx && oi < ai)) { mx = om; ai = oi; }
    }
    float sum = 0.f;
    for (int c = s; c < 81; c += 4) sum += __expf(row[4 + c] - mx);
    sum += __shfl_xor(sum, 1);
    sum += __shfl_xor(sum, 2);
    if (s == 0) {
      float sc = 1.0f / sum;
      u32 kv = INVK;
      if (ai != 0 && sc >= 0.00985f) kv = ~__float_as_uint(sc);  // margin; exact recheck later
      keyA[(size_t)b * Nn + n0 + g] = kv;
    }
  }
}

// ============================================================
// w3: per-image: inline LDS hist (R6-proven) + cumsum + chunk boundaries
// + LDS-counter compaction -> chunkCnt, clist
// ============================================================
__global__ __launch_bounds__(1024) void w3_cutcompact(const u32* __restrict__ keyA,
                                                      int* __restrict__ chunkCntG,
                                                      int* __restrict__ clist) {
  __shared__ int hist[NBIN];       // counts -> inclusive cumsum
  __shared__ int chunkIdL[NBIN];
  __shared__ int wsum[16];
  __shared__ int sBinHi;
  __shared__ int sCnt[NCHK];
  const int b = blockIdx.x;
  const int tid = threadIdx.x;
  const int lane = tid & 63, wid = tid >> 6;
  const u32* kb = keyA + (size_t)b * Nn;

  // --- inline histogram (R6-proven LDS atomics) ---
  for (int i = tid; i < NBIN; i += 1024) hist[i] = 0;
  chunkIdL[2 * tid] = 255;
  chunkIdL[2 * tid + 1] = 255;
  if (tid < NCHK) sCnt[tid] = 0;
  __syncthreads();
  for (int i = tid; i < Nn; i += 1024) {
    u32 kv = kb[i];
    u32 bin = (kv - 0xC0000000u) >> 15;    // INVK -> huge (skipped)
    if (bin < NBIN) atomicAdd(&hist[bin], 1);
  }
  __syncthreads();

  // --- inclusive prefix scan (proven R6 code) ---
  int h0 = hist[2 * tid], h1 = hist[2 * tid + 1];
  int v = h0 + h1;
  int iv = v;
  #pragma unroll
  for (int d = 1; d < 64; d <<= 1) {
    int t = __shfl_up(iv, d);
    if (lane >= d) iv += t;
  }
  if (lane == 63) wsum[wid] = iv;
  __syncthreads();
  if (tid < 16) {
    int w = wsum[tid];
    #pragma unroll
    for (int d = 1; d < 16; d <<= 1) {
      int t = __shfl_up(w, d);
      if ((int)tid >= d) w += t;
    }
    wsum[tid] = w;
  }
  __syncthreads();
  int excl = iv - v + (wid > 0 ? wsum[wid - 1] : 0);
  hist[2 * tid] = excl + h0;
  hist[2 * tid + 1] = excl + h0 + h1;
  __syncthreads();

  // --- chunk boundaries (proven R8 loop) ---
  int binLo = -1, cumBase = 0;
  for (int c = 0; c < NCHK; ++c) {
    if (tid == 0) sBinHi = binLo;
    __syncthreads();
    const int limit = cumBase + CH;
    int loc = -1;
    if (hist[2 * tid] <= limit) loc = 2 * tid;
    if (hist[2 * tid + 1] <= limit) loc = 2 * tid + 1;
    if (loc > binLo) atomicMax(&sBinHi, loc);
    __syncthreads();
    int binHi = sBinHi;
    if (binHi == binLo) binHi = binLo + 1;   // oversized-single-bin fallback
    if (2 * tid > binLo && 2 * tid <= binHi) chunkIdL[2 * tid] = c;
    if (2 * tid + 1 > binLo && 2 * tid + 1 <= binHi) chunkIdL[2 * tid + 1] = c;
    cumBase = hist[(binHi < NBIN ? binHi : NBIN - 1)];
    binLo = binHi;
    __syncthreads();
  }

  // --- compaction with LDS counters (wave-aggregated) ---
  for (int i0 = 0; i0 < Nn; i0 += 1024) {
    int i = i0 + tid;
    int c = 255;
    if (i < Nn) {
      u32 kv = kb[i];
      u32 bin = (kv - 0xC0000000u) >> 15;
      if (bin < NBIN) c = chunkIdL[bin];
    }
    #pragma unroll
    for (int cc = 0; cc < NCHK; ++cc) {
      bool pred = (c == cc);
      u64 m = __ballot(pred);
      if (m) {
        int base = 0;
        if (lane == 0) base = atomicAdd(&sCnt[cc], (int)__popcll(m));
        base = __shfl(base, 0);
        if (pred) {
          int off = (int)__popcll(m & ((1ULL << lane) - 1ULL));
          int p = base + off;
          if (p < CH) clist[b * CHTOT + cc * CH + p] = i;
        }
      }
    }
  }
  __syncthreads();
  if (tid < NCHK) chunkCntG[b * NCHK + tid] = sCnt[tid];
}

// ============================================================
// w4: full-grid exact f64 rescore of chunks 0..1 only
// (4 lanes/candidate; summation order bit-identical to R2)
// ============================================================
__global__ __launch_bounds__(256) void w4_rescore(const float* __restrict__ logits,
                                                  const float* __restrict__ anchors,
                                                  const int* __restrict__ clist,
                                                  const int* __restrict__ chunkCntG,
                                                  double* __restrict__ boxesd,
                                                  int* __restrict__ clsd,
                                                  u64* __restrict__ ekeysG) {
  const int tid = threadIdx.x;
  const int bx = blockIdx.x;
  const int b = bx >> 6;
  const int blk = bx & 63;
  const int c = blk >> 5;                 // 0..1
  const int sb = (blk & 31) << 6;
  int cnt = chunkCntG[b * NCHK + c];
  cnt = cnt > CH ? CH : cnt;
  const int g = tid >> 2, s = tid & 3;
  const int slot = sb + g;
  u64 K = ~0ULL;
  if (slot < cnt) {
    const int n = clist[b * CHTOT + c * CH + slot];
    const float* row = logits + ((size_t)b * Nn + n) * 85;
    float rv[21];
    float mx = -1e30f; int ai = 1000;
    #pragma unroll
    for (int q = 0; q < 21; ++q) {
      int cc = s + 4 * q;
      float vv = (cc < 81) ? row[4 + cc] : -1e30f;
      rv[q] = vv;
      if (cc < 81 && vv > mx) { mx = vv; ai = cc; }
    }
    #pragma unroll
    for (int d = 1; d <= 2; d <<= 1) {
      float om = __shfl_xor(mx, d);
      int oi = __shfl_xor(ai, d);
      if (om > mx || (om == mx && oi < ai)) { mx = om; ai = oi; }
    }
    double sum = 0.0;
    #pragma unroll
    for (int q = 0; q < 21; ++q) {
      if (s + 4 * q < 81) sum += fast_exp_d((double)rv[q] - (double)mx);
    }
    sum += __shfl_xor(sum, 1);
    sum += __shfl_xor(sum, 2);
    if (s == 0) {
      double score = 1.0 / sum;
      if (ai != 0 && score >= 0.01) {
        float4 a4 = reinterpret_cast<const float4*>(anchors)[n];
        double ax1 = a4.x, ay1 = a4.y, ax2 = a4.z, ay2 = a4.w;
        double cx = (ax2 + ax1) * 0.5, cy = (ay2 + ay1) * 0.5;
        double ww = ax2 - ax1, hh = ay2 - ay1;
        double ctrx = (double)row[0] * ww + cx;
        double ctry = (double)row[1] * hh + cy;
        double szx = fast_exp_d((double)row[2]) * ww;
        double szy = fast_exp_d((double)row[3]) * hh;
        double* bp = boxesd + (size_t)(b * Nn + n) * 4;
        bp[0] = clip01(ctrx - szx * 0.5);
        bp[1] = clip01(ctry - szy * 0.5);
        bp[2] = clip01(ctrx + szx * 0.5);
        bp[3] = clip01(ctry + szy * 0.5);
        clsd[b * Nn + n] = ai;
        u64 sb2 = (u64)__double_as_longlong(score);
        u64 e4 = (sb2 >> 52) - 1015ULL;
        u64 mant45 = (sb2 & ((1ULL << 52) - 1)) >> 7;
        u64 flip = (~((e4 << 45) | mant45)) & ((1ULL << 49) - 1);
        K = (flip << 15) | (u64)n;
      }
    }
  }
  if (s == 0) ekeysG[(size_t)b * CHPRE + c * CH + slot] = K;
}

// ============================================================
// w5: per-image: chunk loop {load (or inline-rescore for c>=2) ->
// bitonic sort -> multi-wave NMS with parallel kill-masks} -> outputs
// ============================================================
__global__ __launch_bounds__(1024) void w5_sortnms(const float* __restrict__ logits,
                                                   const float* __restrict__ anchors,
                                                   const u64* __restrict__ ekeysG,
                                                   const int* __restrict__ chunkCntG,
                                                   const int* __restrict__ clist,
                                                   double* __restrict__ boxesd,
                                                   int* __restrict__ clsd,
                                                   float* __restrict__ out) {
  __shared__ u64 ek[CH];
  __shared__ double bbuf[2][64][4];
  __shared__ u64 awv[16];
  __shared__ u64 killm[64];
  __shared__ double selBox[MAXB][4];
  __shared__ double selArea[MAXB];
  __shared__ float selScore[MAXB];
  __shared__ int selIdx[MAXB];
  __shared__ int sS;
  const int b = blockIdx.x;
  const int tid = threadIdx.x;
  const int lane = tid & 63, wid = tid >> 6;
  const double THR = 0.45;
  if (tid == 0) sS = 0;
  __syncthreads();

  for (int c = 0; c < NCHK; ++c) {
    if (sS >= MAXB) break;
    int cnt = chunkCntG[b * NCHK + c];
    cnt = cnt > CH ? CH : cnt;
    if (cnt == 0) break;

    if (c < CHK_PRE) {
      for (int i = tid; i < CH; i += 1024) ek[i] = ekeysG[(size_t)b * CHPRE + c * CH + i];
      __syncthreads();
    } else {
      // inline exact rescore (R6-proven code, rare path)
      for (int i = tid; i < CH; i += 1024) ek[i] = ~0ULL;
      __syncthreads();
      const int g = tid >> 2, s4 = tid & 3;
      #pragma unroll 1
      for (int pass = 0; pass < CH / 256; ++pass) {
        int slot = pass * 256 + g;
        if (slot < cnt) {
          const int n = clist[b * CHTOT + c * CH + slot];
          const float* row = logits + ((size_t)b * Nn + n) * 85;
          float rv[21];
          float mx = -1e30f; int ai = 1000;
          #pragma unroll
          for (int q = 0; q < 21; ++q) {
            int cc = s4 + 4 * q;
            float vv = (cc < 81) ? row[4 + cc] : -1e30f;
            rv[q] = vv;
            if (cc < 81 && vv > mx) { mx = vv; ai = cc; }
          }
          #pragma unroll
          for (int d = 1; d <= 2; d <<= 1) {
            float om = __shfl_xor(mx, d);
            int oi = __shfl_xor(ai, d);
            if (om > mx || (om == mx && oi < ai)) { mx = om; ai = oi; }
          }
          double sum = 0.0;
          #pragma unroll
          for (int q = 0; q < 21; ++q) {
            if (s4 + 4 * q < 81) sum += fast_exp_d((double)rv[q] - (double)mx);
          }
          sum += __shfl_xor(sum, 1);
          sum += __shfl_xor(sum, 2);
          if (s4 == 0) {
            u64 K = ~0ULL;
            double score = 1.0 / sum;
            if (ai != 0 && score >= 0.01) {
              float4 a4 = reinterpret_cast<const float4*>(anchors)[n];
              double ax1 = a4.x, ay1 = a4.y, ax2 = a4.z, ay2 = a4.w;
              double cx = (ax2 + ax1) * 0.5, cy = (ay2 + ay1) * 0.5;
              double ww = ax2 - ax1, hh = ay2 - ay1;
              double ctrx = (double)row[0] * ww + cx;
              double ctry = (double)row[1] * hh + cy;
              double szx = fast_exp_d((double)row[2]) * ww;
              double szy = fast_exp_d((double)row[3]) * hh;
              double* bp = boxesd + (size_t)(b * Nn + n) * 4;
              bp[0] = clip01(ctrx - szx * 0.5);
              bp[1] = clip01(ctry - szy * 0.5);
              bp[2] = clip01(ctrx + szx * 0.5);
              bp[3] = clip01(ctry + szy * 0.5);
              clsd[b * Nn + n] = ai;
              u64 sb2 = (u64)__double_as_longlong(score);
              u64 e4 = (sb2 >> 52) - 1015ULL;
              u64 mant45 = (sb2 & ((1ULL << 52) - 1)) >> 7;
              u64 flip = (~((e4 << 45) | mant45)) & ((1ULL << 49) - 1);
              K = (flip << 15) | (u64)n;
            }
            ek[slot] = K;
          }
        }
      }
      __syncthreads();
    }

    // bitonic sort of first P2 elements (rest all-invalid pads)
    int P2 = 64;
    while (P2 < cnt) P2 <<= 1;
    for (int k = 2; k <= P2; k <<= 1) {
      for (int j = k >> 1; j >= 1; j >>= 1) {
        if (tid < (P2 >> 1)) {
          int l = ((tid & ~(j - 1)) << 1) | (tid & (j - 1));
          int r = l | j;
          bool up = ((l & k) == 0);
          u64 a = ek[l], bbv = ek[r];
          if ((a > bbv) == up) { ek[l] = bbv; ek[r] = a; }
        }
        __syncthreads();
      }
    }

    // ---- multi-wave NMS, parallel kill-masks ----
    int pos = 0, bf = 0;
    if (tid < 256) {
      int ci = tid >> 2, comp = tid & 3;
      u64 Kc = ek[ci];
      double vv = 0.0;
      if (Kc != ~0ULL) vv = boxesd[(size_t)(b * Nn + (int)(Kc & 0x7FFF)) * 4 + comp];
      bbuf[0][ci][comp] = vv;
    }
    __syncthreads();
    for (;;) {
      int S = sS;
      if (S >= MAXB || pos >= CH) break;
      u64 K = ek[pos + lane];
      bool valid = (K != ~0ULL);
      if (!__any(valid)) break;

      // prefetch next batch's boxes (overlaps IoU math)
      if (tid < 256 && pos + 64 < CH) {
        int ci = tid >> 2, comp = tid & 3;
        u64 Kc = ek[pos + 64 + ci];
        double vv = 0.0;
        if (Kc != ~0ULL) vv = boxesd[(size_t)(b * Nn + (int)(Kc & 0x7FFF)) * 4 + comp];
        bbuf[bf ^ 1][ci][comp] = vv;
      }

      double cx1 = bbuf[bf][lane][0], cy1 = bbuf[bf][lane][1];
      double cx2 = bbuf[bf][lane][2], cy2 = bbuf[bf][lane][3];
      double carea = (cx2 - cx1) * (cy2 - cy1);

      // phase 1: vs committed selections (wave wid handles slice)
      bool aliveL = true;
      for (int k = wid; k < S; k += 16) {
        double ltx = fmax(selBox[k][0], cx1), lty = fmax(selBox[k][1], cy1);
        double rbx = fmin(selBox[k][2], cx2), rby = fmin(selBox[k][3], cy2);
        double w = rbx - ltx; w = w < 0 ? 0 : w;
        double h = rby - lty; h = h < 0 ? 0 : h;
        double inter = w * h;
        double denom = selArea[k] + carea - inter + 1e-9;
        if (inter > THR * denom) aliveL = false;
      }
      u64 aw = __ballot(aliveL);
      if (lane == 0) awv[wid] = aw;

      // phase 1.5: intra-batch kill-masks (wave wid owns j = 4*wid..4*wid+3)
      #pragma unroll
      for (int q = 0; q < 4; ++q) {
        int j = (wid << 2) | q;
        double jx1 = bbuf[bf][j][0], jy1 = bbuf[bf][j][1];
        double jx2 = bbuf[bf][j][2], jy2 = bbuf[bf][j][3];
        double jar = (jx2 - jx1) * (jy2 - jy1);
        double ltx = fmax(jx1, cx1), lty = fmax(jy1, cy1);
        double rbx = fmin(jx2, cx2), rby = fmin(jy2, cy2);
        double w = rbx - ltx; w = w < 0 ? 0 : w;
        double h = rby - lty; h = h < 0 ? 0 : h;
        double inter = w * h;
        double denom = jar + carea - inter + 1e-9;
        u64 km = __ballot(inter > THR * denom);
        if (lane == 0) killm[j] = km;
      }
      __syncthreads();

      // phase 2: wave 0, pure mask propagation (decisions bit-identical)
      if (tid < 64) {
        u64 alive = __ballot(valid);
        #pragma unroll
        for (int w = 0; w < 16; ++w) alive &= awv[w];
        u64 m = alive;
        int Sl = S;
        while (m != 0 && Sl < MAXB) {
          int j = __ffsll((unsigned long long)m) - 1;
          if (lane == 0) {
            double jx1 = bbuf[bf][j][0], jy1 = bbuf[bf][j][1];
            double jx2 = bbuf[bf][j][2], jy2 = bbuf[bf][j][3];
            u64 Kj = ek[pos + j];
            u64 key49 = (~(Kj >> 15)) & ((1ULL << 49) - 1);
            u64 e = (key49 >> 45) + 1015ULL;
            u64 mant = (key49 & ((1ULL << 45) - 1)) << 7;
            selBox[Sl][0] = jx1; selBox[Sl][1] = jy1;
            selBox[Sl][2] = jx2; selBox[Sl][3] = jy2;
            selArea[Sl] = (jx2 - jx1) * (jy2 - jy1);
            selScore[Sl] = (float)__longlong_as_double((long long)((e << 52) | mant));
            selIdx[Sl] = (int)(Kj & 0x7FFF);
          }
          Sl++;
          m &= ~(1ULL << j);
          m &= ~killm[j];
        }
        if (lane == 0) sS = Sl;
      }
      __syncthreads();
      bf ^= 1;
      pos += 64;
    }
    __syncthreads();
  }

  // --- outputs (whole buffer read as f32 by harness) ---
  const int S = sS;
  float* det_boxes = out;
  float* det_classes = out + Bn * MAXB * 4;
  float* det_scores = out + Bn * MAXB * 4 + Bn * MAXB;
  float* det_num = out + Bn * MAXB * 4 + 2 * Bn * MAXB;
  for (int k = tid; k < MAXB; k += 1024) {
    int o = b * MAXB + k;
    if (k < S) {
      det_boxes[o * 4 + 0] = (float)selBox[k][0];
      det_boxes[o * 4 + 1] = (float)selBox[k][1];
      det_boxes[o * 4 + 2] = (float)selBox[k][2];
      det_boxes[o * 4 + 3] = (float)selBox[k][3];
      det_classes[o] = (float)clsd[b * Nn + selIdx[k]];
      det_scores[o] = selScore[k];
    } else {
      det_boxes[o * 4 + 0] = 0.f; det_boxes[o * 4 + 1] = 0.f;
      det_boxes[o * 4 + 2] = 0.f; det_boxes[o * 4 + 3] = 0.f;
      det_classes[o] = 0.f;
      det_scores[o] = 0.f;
    }
  }
  if (tid == 0) det_num[b] = (float)S;
}

// ============================================================
extern "C" void kernel_launch(void* const* d_in, const int* in_sizes, int n_in,
                              void* d_out, int out_size, void* d_ws, size_t ws_size,
                              hipStream_t stream) {
  const float* logits = (const float*)d_in[0];
  const float* anchors = (const float*)d_in[1];
  float* out = (float*)d_out;
  char* ws = (char*)d_ws;

  double* boxesd = (double*)ws;
  size_t off = (size_t)Bn * Nn * 4 * sizeof(double);
  int* clsd    = (int*)(ws + off);  off += (size_t)Bn * Nn * sizeof(int);
  u32* keyA    = (u32*)(ws + off);  off += (size_t)Bn * Nn * sizeof(u32);
  int* chunkCnt= (int*)(ws + off);  off += (size_t)Bn * NCHK * sizeof(int);
  int* clist   = (int*)(ws + off);  off += (size_t)Bn * CHTOT * sizeof(int);
  u64* ekeysG  = (u64*)(ws + off);

  w1_score     <<<dim3(Bn * 384), dim3(256),  0, stream>>>(logits, keyA);
  w3_cutcompact<<<dim3(Bn),       dim3(1024), 0, stream>>>(keyA, chunkCnt, clist);
  w4_rescore   <<<dim3(Bn * 64),  dim3(256),  0, stream>>>(logits, anchors, clist, chunkCnt,
                                                           boxesd, clsd, ekeysG);
  w5_sortnms   <<<dim3(Bn),       dim3(1024), 0, stream>>>(logits, anchors, ekeysG, chunkCnt,
                                                           clist, boxesd, clsd, out);
}

// Round 13
// 171.201 us; speedup vs baseline: 1.2088x; 1.0207x over previous
//
#include <hip/hip_runtime.h>

#define Bn 32
#define Nn 24564
#define MAXB 200
#define NBIN 2048
#define CH 2048
#define NCHK 4
#define CHK_PRE 2
#define CHTOT (NCHK * CH)
#define CHPRE (CHK_PRE * CH)
#define INVK 0xFFFFFFFFu

typedef unsigned long long u64;
typedef unsigned int u32;

// -------- accurate double exp (rel err ~6e-15) -- bit-stable since R2 --------
__device__ inline double fast_exp_d(double x) {
  const double LOG2E = 1.4426950408889634074;
  const double LN2   = 0.69314718055994530942;
  double t = x * LOG2E;
  double fi = floor(t + 0.5);
  double f = (t - fi) * LN2;
  double p = 2.505210838544172e-8;
  p = p * f + 2.755731922398589e-7;
  p = p * f + 2.7557319223985893e-6;
  p = p * f + 2.48015873015873e-5;
  p = p * f + 1.984126984126984e-4;
  p = p * f + 1.3888888888888889e-3;
  p = p * f + 8.333333333333333e-3;
  p = p * f + 4.1666666666666664e-2;
  p = p * f + 1.6666666666666666e-1;
  p = p * f + 0.5;
  p = p * f + 1.0;
  p = p * f + 1.0;
  long long e = (long long)fi;
  return p * __longlong_as_double((e + 1023LL) << 52);
}

__device__ inline double clip01(double v) {
  return v < 0.0 ? 0.0 : (v > 1.0 ? 1.0 : v);
}

// ============================================================
// x1: f32 scoring -> u32 key per anchor (proven ~54us, 78% HBM)
// ============================================================
__global__ __launch_bounds__(256) void x1_score(const float* __restrict__ logits,
                                                u32* __restrict__ keyA) {
  __shared__ float lds[64 * 85];
  const int tid = threadIdx.x;
  const int bx = blockIdx.x;
  const int b = bx / 384;
  const int n0 = (bx % 384) << 6;
  int cnt = Nn - n0;
  cnt = cnt > 64 ? 64 : cnt;
  const int nf4 = (cnt * 85) >> 2;
  const float4* src = reinterpret_cast<const float4*>(logits + ((size_t)b * Nn + n0) * 85);
  float4* dst = reinterpret_cast<float4*>(lds);
  for (int i = tid; i < nf4; i += 256) dst[i] = src[i];
  __syncthreads();

  const int g = tid >> 2;
  const int s = tid & 3;
  if (g < cnt) {
    const float* row = lds + g * 85;
    float mx = -1e30f; int ai = 1000;
    for (int c = s; c < 81; c += 4) {
      float v = row[4 + c];
      if (v > mx) { mx = v; ai = c; }
    }
    #pragma unroll
    for (int d = 1; d <= 2; d <<= 1) {
      float om = __shfl_xor(mx, d);
      int oi = __shfl_xor(ai, d);
      if (om > mx || (om == mx && oi < ai)) { mx = om; ai = oi; }
    }
    float sum = 0.f;
    for (int c = s; c < 81; c += 4) sum += __expf(row[4 + c] - mx);
    sum += __shfl_xor(sum, 1);
    sum += __shfl_xor(sum, 2);
    if (s == 0) {
      float sc = 1.0f / sum;
      u32 kv = INVK;
      if (ai != 0 && sc >= 0.00985f) kv = ~__float_as_uint(sc);  // margin; exact recheck later
      keyA[(size_t)b * Nn + n0 + g] = kv;
    }
  }
}

// ============================================================
// x3: per-image: inline LDS hist + cumsum + chunk boundaries
// + LDS-counter compaction -> chunkCnt, clist (verbatim R12)
// ============================================================
__global__ __launch_bounds__(1024) void x3_cutcompact(const u32* __restrict__ keyA,
                                                      int* __restrict__ chunkCntG,
                                                      int* __restrict__ clist) {
  __shared__ int hist[NBIN];
  __shared__ int chunkIdL[NBIN];
  __shared__ int wsum[16];
  __shared__ int sBinHi;
  __shared__ int sCnt[NCHK];
  const int b = blockIdx.x;
  const int tid = threadIdx.x;
  const int lane = tid & 63, wid = tid >> 6;
  const u32* kb = keyA + (size_t)b * Nn;

  for (int i = tid; i < NBIN; i += 1024) hist[i] = 0;
  chunkIdL[2 * tid] = 255;
  chunkIdL[2 * tid + 1] = 255;
  if (tid < NCHK) sCnt[tid] = 0;
  __syncthreads();
  for (int i = tid; i < Nn; i += 1024) {
    u32 kv = kb[i];
    u32 bin = (kv - 0xC0000000u) >> 15;
    if (bin < NBIN) atomicAdd(&hist[bin], 1);
  }
  __syncthreads();

  int h0 = hist[2 * tid], h1 = hist[2 * tid + 1];
  int v = h0 + h1;
  int iv = v;
  #pragma unroll
  for (int d = 1; d < 64; d <<= 1) {
    int t = __shfl_up(iv, d);
    if (lane >= d) iv += t;
  }
  if (lane == 63) wsum[wid] = iv;
  __syncthreads();
  if (tid < 16) {
    int w = wsum[tid];
    #pragma unroll
    for (int d = 1; d < 16; d <<= 1) {
      int t = __shfl_up(w, d);
      if ((int)tid >= d) w += t;
    }
    wsum[tid] = w;
  }
  __syncthreads();
  int excl = iv - v + (wid > 0 ? wsum[wid - 1] : 0);
  hist[2 * tid] = excl + h0;
  hist[2 * tid + 1] = excl + h0 + h1;
  __syncthreads();

  int binLo = -1, cumBase = 0;
  for (int c = 0; c < NCHK; ++c) {
    if (tid == 0) sBinHi = binLo;
    __syncthreads();
    const int limit = cumBase + CH;
    int loc = -1;
    if (hist[2 * tid] <= limit) loc = 2 * tid;
    if (hist[2 * tid + 1] <= limit) loc = 2 * tid + 1;
    if (loc > binLo) atomicMax(&sBinHi, loc);
    __syncthreads();
    int binHi = sBinHi;
    if (binHi == binLo) binHi = binLo + 1;   // oversized-single-bin fallback
    if (2 * tid > binLo && 2 * tid <= binHi) chunkIdL[2 * tid] = c;
    if (2 * tid + 1 > binLo && 2 * tid + 1 <= binHi) chunkIdL[2 * tid + 1] = c;
    cumBase = hist[(binHi < NBIN ? binHi : NBIN - 1)];
    binLo = binHi;
    __syncthreads();
  }

  for (int i0 = 0; i0 < Nn; i0 += 1024) {
    int i = i0 + tid;
    int c = 255;
    if (i < Nn) {
      u32 kv = kb[i];
      u32 bin = (kv - 0xC0000000u) >> 15;
      if (bin < NBIN) c = chunkIdL[bin];
    }
    #pragma unroll
    for (int cc = 0; cc < NCHK; ++cc) {
      bool pred = (c == cc);
      u64 m = __ballot(pred);
      if (m) {
        int base = 0;
        if (lane == 0) base = atomicAdd(&sCnt[cc], (int)__popcll(m));
        base = __shfl(base, 0);
        if (pred) {
          int off = (int)__popcll(m & ((1ULL << lane) - 1ULL));
          int p = base + off;
          if (p < CH) clist[b * CHTOT + cc * CH + p] = i;
        }
      }
    }
  }
  __syncthreads();
  if (tid < NCHK) chunkCntG[b * NCHK + tid] = sCnt[tid];
}

// ============================================================
// x4: full-grid exact f64 rescore of chunks 0..1 FUSED with 256-element
// presort: each block owns one 256-candidate segment, rescans (bit-identical
// math/order), bitonic-sorts its keys in LDS, writes a SORTED run.
// ============================================================
__global__ __launch_bounds__(256) void x4_rescore(const float* __restrict__ logits,
                                                  const float* __restrict__ anchors,
                                                  const int* __restrict__ clist,
                                                  const int* __restrict__ chunkCntG,
                                                  double* __restrict__ boxesd,
                                                  int* __restrict__ clsd,
                                                  u64* __restrict__ ekeysG) {
  __shared__ u64 ekseg[256];
  const int tid = threadIdx.x;
  const int bx = blockIdx.x;
  const int b = bx >> 4;
  const int blk = bx & 15;
  const int c = blk >> 3;                 // 0..1
  const int seg = blk & 7;                // 0..7
  int cnt = chunkCntG[b * NCHK + c];
  cnt = cnt > CH ? CH : cnt;
  const int g = tid >> 2, s = tid & 3;

  #pragma unroll 1
  for (int pass = 0; pass < 4; ++pass) {
    const int slot = seg * 256 + pass * 64 + g;
    u64 K = ~0ULL;
    if (slot < cnt) {
      const int n = clist[b * CHTOT + c * CH + slot];
      const float* row = logits + ((size_t)b * Nn + n) * 85;
      float rv[21];
      float mx = -1e30f; int ai = 1000;
      #pragma unroll
      for (int q = 0; q < 21; ++q) {
        int cc = s + 4 * q;
        float vv = (cc < 81) ? row[4 + cc] : -1e30f;
        rv[q] = vv;
        if (cc < 81 && vv > mx) { mx = vv; ai = cc; }
      }
      #pragma unroll
      for (int d = 1; d <= 2; d <<= 1) {
        float om = __shfl_xor(mx, d);
        int oi = __shfl_xor(ai, d);
        if (om > mx || (om == mx && oi < ai)) { mx = om; ai = oi; }
      }
      double sum = 0.0;
      #pragma unroll
      for (int q = 0; q < 21; ++q) {
        if (s + 4 * q < 81) sum += fast_exp_d((double)rv[q] - (double)mx);
      }
      sum += __shfl_xor(sum, 1);
      sum += __shfl_xor(sum, 2);
      if (s == 0) {
        double score = 1.0 / sum;
        if (ai != 0 && score >= 0.01) {
          float4 a4 = reinterpret_cast<const float4*>(anchors)[n];
          double ax1 = a4.x, ay1 = a4.y, ax2 = a4.z, ay2 = a4.w;
          double cx = (ax2 + ax1) * 0.5, cy = (ay2 + ay1) * 0.5;
          double ww = ax2 - ax1, hh = ay2 - ay1;
          double ctrx = (double)row[0] * ww + cx;
          double ctry = (double)row[1] * hh + cy;
          double szx = fast_exp_d((double)row[2]) * ww;
          double szy = fast_exp_d((double)row[3]) * hh;
          double* bp = boxesd + (size_t)(b * Nn + n) * 4;
          bp[0] = clip01(ctrx - szx * 0.5);
          bp[1] = clip01(ctry - szy * 0.5);
          bp[2] = clip01(ctrx + szx * 0.5);
          bp[3] = clip01(ctry + szy * 0.5);
          clsd[b * Nn + n] = ai;
          u64 sb2 = (u64)__double_as_longlong(score);
          u64 e4 = (sb2 >> 52) - 1015ULL;
          u64 mant45 = (sb2 & ((1ULL << 52) - 1)) >> 7;
          u64 flip = (~((e4 << 45) | mant45)) & ((1ULL << 49) - 1);
          K = (flip << 15) | (u64)n;
        }
      }
    }
    if (s == 0) ekseg[pass * 64 + g] = K;
  }
  __syncthreads();

  // 256-element bitonic sort, ascending (36 stages, high occupancy)
  for (int k = 2; k <= 256; k <<= 1) {
    for (int j = k >> 1; j >= 1; j >>= 1) {
      if (tid < 128) {
        int l = ((tid & ~(j - 1)) << 1) | (tid & (j - 1));
        int r = l | j;
        bool up = ((l & k) == 0);
        u64 a = ekseg[l], bv = ekseg[r];
        if ((a > bv) == up) { ekseg[l] = bv; ekseg[r] = a; }
      }
      __syncthreads();
    }
  }
  u64* dstp = ekeysG + (size_t)b * CHPRE + c * CH + seg * 256;
  for (int i = tid; i < 256; i += 256) dstp[i] = ekseg[i];
}

// ============================================================
// x5: per-image: chunk loop {load 8 sorted runs -> 30-stage 8-way bitonic
// MERGE (c<2) or inline-rescore + full sort (c>=2) -> multi-wave NMS with
// parallel kill-masks} -> outputs
// ============================================================
__global__ __launch_bounds__(1024) void x5_sortnms(const float* __restrict__ logits,
                                                   const float* __restrict__ anchors,
                                                   const u64* __restrict__ ekeysG,
                                                   const int* __restrict__ chunkCntG,
                                                   const int* __restrict__ clist,
                                                   double* __restrict__ boxesd,
                                                   int* __restrict__ clsd,
                                                   float* __restrict__ out) {
  __shared__ u64 ek[CH];
  __shared__ double bbuf[2][64][4];
  __shared__ u64 awv[16];
  __shared__ u64 killm[64];
  __shared__ double selBox[MAXB][4];
  __shared__ double selArea[MAXB];
  __shared__ float selScore[MAXB];
  __shared__ int selIdx[MAXB];
  __shared__ int sS;
  const int b = blockIdx.x;
  const int tid = threadIdx.x;
  const int lane = tid & 63, wid = tid >> 6;
  const double THR = 0.45;
  if (tid == 0) sS = 0;
  __syncthreads();

  for (int c = 0; c < NCHK; ++c) {
    if (sS >= MAXB) break;
    int cnt = chunkCntG[b * NCHK + c];
    cnt = cnt > CH ? CH : cnt;
    if (cnt == 0) break;

    if (c < CHK_PRE) {
      // load 8 pre-sorted 256-runs
      for (int i = tid; i < CH; i += 1024) ek[i] = ekeysG[(size_t)b * CHPRE + c * CH + i];
      __syncthreads();
      // 3 merge rounds: L = 256, 512, 1024 (crossing + half-cleaner cascade)
      for (int L = 256; L <= 1024; L <<= 1) {
        int pair = tid / L, i = tid % L;
        int base = pair * 2 * L;
        int l = base + i, r = base + 2 * L - 1 - i;
        u64 a = ek[l], bv = ek[r];
        if (a > bv) { ek[l] = bv; ek[r] = a; }
        __syncthreads();
        for (int j = L >> 1; j >= 1; j >>= 1) {
          int ll = ((tid & ~(j - 1)) << 1) | (tid & (j - 1));
          int rr = ll | j;
          u64 x = ek[ll], y = ek[rr];
          if (x > y) { ek[ll] = y; ek[rr] = x; }
          __syncthreads();
        }
      }
    } else {
      // inline exact rescore (R6-proven code, rare path)
      for (int i = tid; i < CH; i += 1024) ek[i] = ~0ULL;
      __syncthreads();
      const int g = tid >> 2, s4 = tid & 3;
      #pragma unroll 1
      for (int pass = 0; pass < CH / 256; ++pass) {
        int slot = pass * 256 + g;
        if (slot < cnt) {
          const int n = clist[b * CHTOT + c * CH + slot];
          const float* row = logits + ((size_t)b * Nn + n) * 85;
          float rv[21];
          float mx = -1e30f; int ai = 1000;
          #pragma unroll
          for (int q = 0; q < 21; ++q) {
            int cc = s4 + 4 * q;
            float vv = (cc < 81) ? row[4 + cc] : -1e30f;
            rv[q] = vv;
            if (cc < 81 && vv > mx) { mx = vv; ai = cc; }
          }
          #pragma unroll
          for (int d = 1; d <= 2; d <<= 1) {
            float om = __shfl_xor(mx, d);
            int oi = __shfl_xor(ai, d);
            if (om > mx || (om == mx && oi < ai)) { mx = om; ai = oi; }
          }
          double sum = 0.0;
          #pragma unroll
          for (int q = 0; q < 21; ++q) {
            if (s4 + 4 * q < 81) sum += fast_exp_d((double)rv[q] - (double)mx);
          }
          sum += __shfl_xor(sum, 1);
          sum += __shfl_xor(sum, 2);
          if (s4 == 0) {
            u64 K = ~0ULL;
            double score = 1.0 / sum;
            if (ai != 0 && score >= 0.01) {
              float4 a4 = reinterpret_cast<const float4*>(anchors)[n];
              double ax1 = a4.x, ay1 = a4.y, ax2 = a4.z, ay2 = a4.w;
              double cx = (ax2 + ax1) * 0.5, cy = (ay2 + ay1) * 0.5;
              double ww = ax2 - ax1, hh = ay2 - ay1;
              double ctrx = (double)row[0] * ww + cx;
              double ctry = (double)row[1] * hh + cy;
              double szx = fast_exp_d((double)row[2]) * ww;
              double szy = fast_exp_d((double)row[3]) * hh;
              double* bp = boxesd + (size_t)(b * Nn + n) * 4;
              bp[0] = clip01(ctrx - szx * 0.5);
              bp[1] = clip01(ctry - szy * 0.5);
              bp[2] = clip01(ctrx + szx * 0.5);
              bp[3] = clip01(ctry + szy * 0.5);
              clsd[b * Nn + n] = ai;
              u64 sb2 = (u64)__double_as_longlong(score);
              u64 e4 = (sb2 >> 52) - 1015ULL;
              u64 mant45 = (sb2 & ((1ULL << 52) - 1)) >> 7;
              u64 flip = (~((e4 << 45) | mant45)) & ((1ULL << 49) - 1);
              K = (flip << 15) | (u64)n;
            }
            ek[slot] = K;
          }
        }
      }
      __syncthreads();
      // full bitonic sort of first P2 elements
      int P2 = 64;
      while (P2 < cnt) P2 <<= 1;
      for (int k = 2; k <= P2; k <<= 1) {
        for (int j = k >> 1; j >= 1; j >>= 1) {
          if (tid < (P2 >> 1)) {
            int l = ((tid & ~(j - 1)) << 1) | (tid & (j - 1));
            int r = l | j;
            bool up = ((l & k) == 0);
            u64 a = ek[l], bbv = ek[r];
            if ((a > bbv) == up) { ek[l] = bbv; ek[r] = a; }
          }
          __syncthreads();
        }
      }
    }

    // ---- multi-wave NMS, parallel kill-masks (verbatim R12) ----
    int pos = 0, bf = 0;
    if (tid < 256) {
      int ci = tid >> 2, comp = tid & 3;
      u64 Kc = ek[ci];
      double vv = 0.0;
      if (Kc != ~0ULL) vv = boxesd[(size_t)(b * Nn + (int)(Kc & 0x7FFF)) * 4 + comp];
      bbuf[0][ci][comp] = vv;
    }
    __syncthreads();
    for (;;) {
      int S = sS;
      if (S >= MAXB || pos >= CH) break;
      u64 K = ek[pos + lane];
      bool valid = (K != ~0ULL);
      if (!__any(valid)) break;

      if (tid < 256 && pos + 64 < CH) {
        int ci = tid >> 2, comp = tid & 3;
        u64 Kc = ek[pos + 64 + ci];
        double vv = 0.0;
        if (Kc != ~0ULL) vv = boxesd[(size_t)(b * Nn + (int)(Kc & 0x7FFF)) * 4 + comp];
        bbuf[bf ^ 1][ci][comp] = vv;
      }

      double cx1 = bbuf[bf][lane][0], cy1 = bbuf[bf][lane][1];
      double cx2 = bbuf[bf][lane][2], cy2 = bbuf[bf][lane][3];
      double carea = (cx2 - cx1) * (cy2 - cy1);

      bool aliveL = true;
      for (int k = wid; k < S; k += 16) {
        double ltx = fmax(selBox[k][0], cx1), lty = fmax(selBox[k][1], cy1);
        double rbx = fmin(selBox[k][2], cx2), rby = fmin(selBox[k][3], cy2);
        double w = rbx - ltx; w = w < 0 ? 0 : w;
        double h = rby - lty; h = h < 0 ? 0 : h;
        double inter = w * h;
        double denom = selArea[k] + carea - inter + 1e-9;
        if (inter > THR * denom) aliveL = false;
      }
      u64 aw = __ballot(aliveL);
      if (lane == 0) awv[wid] = aw;

      #pragma unroll
      for (int q = 0; q < 4; ++q) {
        int j = (wid << 2) | q;
        double jx1 = bbuf[bf][j][0], jy1 = bbuf[bf][j][1];
        double jx2 = bbuf[bf][j][2], jy2 = bbuf[bf][j][3];
        double jar = (jx2 - jx1) * (jy2 - jy1);
        double ltx = fmax(jx1, cx1), lty = fmax(jy1, cy1);
        double rbx = fmin(jx2, cx2), rby = fmin(jy2, cy2);
        double w = rbx - ltx; w = w < 0 ? 0 : w;
        double h = rby - lty; h = h < 0 ? 0 : h;
        double inter = w * h;
        double denom = jar + carea - inter + 1e-9;
        u64 km = __ballot(inter > THR * denom);
        if (lane == 0) killm[j] = km;
      }
      __syncthreads();

      if (tid < 64) {
        u64 alive = __ballot(valid);
        #pragma unroll
        for (int w = 0; w < 16; ++w) alive &= awv[w];
        u64 m = alive;
        int Sl = S;
        while (m != 0 && Sl < MAXB) {
          int j = __ffsll((unsigned long long)m) - 1;
          if (lane == 0) {
            double jx1 = bbuf[bf][j][0], jy1 = bbuf[bf][j][1];
            double jx2 = bbuf[bf][j][2], jy2 = bbuf[bf][j][3];
            u64 Kj = ek[pos + j];
            u64 key49 = (~(Kj >> 15)) & ((1ULL << 49) - 1);
            u64 e = (key49 >> 45) + 1015ULL;
            u64 mant = (key49 & ((1ULL << 45) - 1)) << 7;
            selBox[Sl][0] = jx1; selBox[Sl][1] = jy1;
            selBox[Sl][2] = jx2; selBox[Sl][3] = jy2;
            selArea[Sl] = (jx2 - jx1) * (jy2 - jy1);
            selScore[Sl] = (float)__longlong_as_double((long long)((e << 52) | mant));
            selIdx[Sl] = (int)(Kj & 0x7FFF);
          }
          Sl++;
          m &= ~(1ULL << j);
          m &= ~killm[j];
        }
        if (lane == 0) sS = Sl;
      }
      __syncthreads();
      bf ^= 1;
      pos += 64;
    }
    __syncthreads();
  }

  // --- outputs (whole buffer read as f32 by harness) ---
  const int S = sS;
  float* det_boxes = out;
  float* det_classes = out + Bn * MAXB * 4;
  float* det_scores = out + Bn * MAXB * 4 + Bn * MAXB;
  float* det_num = out + Bn * MAXB * 4 + 2 * Bn * MAXB;
  for (int k = tid; k < MAXB; k += 1024) {
    int o = b * MAXB + k;
    if (k < S) {
      det_boxes[o * 4 + 0] = (float)selBox[k][0];
      det_boxes[o * 4 + 1] = (float)selBox[k][1];
      det_boxes[o * 4 + 2] = (float)selBox[k][2];
      det_boxes[o * 4 + 3] = (float)selBox[k][3];
      det_classes[o] = (float)clsd[b * Nn + selIdx[k]];
      det_scores[o] = selScore[k];
    } else {
      det_boxes[o * 4 + 0] = 0.f; det_boxes[o * 4 + 1] = 0.f;
      det_boxes[o * 4 + 2] = 0.f; det_boxes[o * 4 + 3] = 0.f;
      det_classes[o] = 0.f;
      det_scores[o] = 0.f;
    }
  }
  if (tid == 0) det_num[b] = (float)S;
}

// ============================================================
extern "C" void kernel_launch(void* const* d_in, const int* in_sizes, int n_in,
                              void* d_out, int out_size, void* d_ws, size_t ws_size,
                              hipStream_t stream) {
  const float* logits = (const float*)d_in[0];
  const float* anchors = (const float*)d_in[1];
  float* out = (float*)d_out;
  char* ws = (char*)d_ws;

  double* boxesd = (double*)ws;
  size_t off = (size_t)Bn * Nn * 4 * sizeof(double);
  int* clsd    = (int*)(ws + off);  off += (size_t)Bn * Nn * sizeof(int);
  u32* keyA    = (u32*)(ws + off);  off += (size_t)Bn * Nn * sizeof(u32);
  int* chunkCnt= (int*)(ws + off);  off += (size_t)Bn * NCHK * sizeof(int);
  int* clist   = (int*)(ws + off);  off += (size_t)Bn * CHTOT * sizeof(int);
  u64* ekeysG  = (u64*)(ws + off);

  x1_score     <<<dim3(Bn * 384), dim3(256),  0, stream>>>(logits, keyA);
  x3_cutcompact<<<dim3(Bn),       dim3(1024), 0, stream>>>(keyA, chunkCnt, clist);
  x4_rescore   <<<dim3(Bn * 16),  dim3(256),  0, stream>>>(logits, anchors, clist, chunkCnt,
                                                           boxesd, clsd, ekeysG);
  x5_sortnms   <<<dim3(Bn),       dim3(1024), 0, stream>>>(logits, anchors, ekeysG, chunkCnt,
                                                           clist, boxesd, clsd, out);
}

// Round 14
// 155.421 us; speedup vs baseline: 1.3315x; 1.1015x over previous
//
#include <hip/hip_runtime.h>

#define Bn 32
#define Nn 24564
#define MAXB 200
#define NBIN 2048
#define CH 2048
#define NCHK 4
#define CHK_PRE 2
#define CHTOT (NCHK * CH)
#define CHPRE (CHK_PRE * CH)
#define INVK 0xFFFFFFFFu

typedef unsigned long long u64;
typedef unsigned int u32;

// -------- accurate double exp (rel err ~6e-15) -- bit-stable since R2 --------
__device__ inline double fast_exp_d(double x) {
  const double LOG2E = 1.4426950408889634074;
  const double LN2   = 0.69314718055994530942;
  double t = x * LOG2E;
  double fi = floor(t + 0.5);
  double f = (t - fi) * LN2;
  double p = 2.505210838544172e-8;
  p = p * f + 2.755731922398589e-7;
  p = p * f + 2.7557319223985893e-6;
  p = p * f + 2.48015873015873e-5;
  p = p * f + 1.984126984126984e-4;
  p = p * f + 1.3888888888888889e-3;
  p = p * f + 8.333333333333333e-3;
  p = p * f + 4.1666666666666664e-2;
  p = p * f + 1.6666666666666666e-1;
  p = p * f + 0.5;
  p = p * f + 1.0;
  p = p * f + 1.0;
  long long e = (long long)fi;
  return p * __longlong_as_double((e + 1023LL) << 52);
}

__device__ inline double clip01(double v) {
  return v < 0.0 ? 0.0 : (v > 1.0 ? 1.0 : v);
}

// ============================================================
// y1: f32 scoring, DIRECT global loads (no LDS round-trip, no barrier).
// Class partition and summation order bit-identical to the proven x1:
// lane s owns c = s, s+4, ..., shfl_xor(1) then (2) combines.
// ============================================================
__global__ __launch_bounds__(256) void y1_score(const float* __restrict__ logits,
                                                u32* __restrict__ keyA) {
  const int tid = threadIdx.x;
  const int bx = blockIdx.x;
  const int b = bx / 384;
  const int n0 = (bx % 384) << 6;
  const int g = tid >> 2, s = tid & 3;
  const int n = n0 + g;
  if (n >= Nn) return;
  const float* row = logits + ((size_t)b * Nn + n) * 85;

  float rv[21];
  float mx = -1e30f; int ai = 1000;
  #pragma unroll
  for (int q = 0; q < 21; ++q) {
    int c = s + 4 * q;
    float v = (c < 81) ? row[4 + c] : -1e30f;
    rv[q] = v;
    if (c < 81 && v > mx) { mx = v; ai = c; }
  }
  #pragma unroll
  for (int d = 1; d <= 2; d <<= 1) {
    float om = __shfl_xor(mx, d);
    int oi = __shfl_xor(ai, d);
    if (om > mx || (om == mx && oi < ai)) { mx = om; ai = oi; }
  }
  float sum = 0.f;
  #pragma unroll
  for (int q = 0; q < 21; ++q) {
    if (s + 4 * q < 81) sum += __expf(rv[q] - mx);
  }
  sum += __shfl_xor(sum, 1);
  sum += __shfl_xor(sum, 2);
  if (s == 0) {
    float sc = 1.0f / sum;
    u32 kv = INVK;
    if (ai != 0 && sc >= 0.00985f) kv = ~__float_as_uint(sc);  // margin; exact recheck later
    keyA[(size_t)b * Nn + n] = kv;
  }
}

// ============================================================
// y3: per-image: inline LDS hist + cumsum + chunk boundaries
// + LDS-counter compaction -> chunkCnt, clist (verbatim R12/R13)
// ============================================================
__global__ __launch_bounds__(1024) void y3_cutcompact(const u32* __restrict__ keyA,
                                                      int* __restrict__ chunkCntG,
                                                      int* __restrict__ clist) {
  __shared__ int hist[NBIN];
  __shared__ int chunkIdL[NBIN];
  __shared__ int wsum[16];
  __shared__ int sBinHi;
  __shared__ int sCnt[NCHK];
  const int b = blockIdx.x;
  const int tid = threadIdx.x;
  const int lane = tid & 63, wid = tid >> 6;
  const u32* kb = keyA + (size_t)b * Nn;

  for (int i = tid; i < NBIN; i += 1024) hist[i] = 0;
  chunkIdL[2 * tid] = 255;
  chunkIdL[2 * tid + 1] = 255;
  if (tid < NCHK) sCnt[tid] = 0;
  __syncthreads();
  for (int i = tid; i < Nn; i += 1024) {
    u32 kv = kb[i];
    u32 bin = (kv - 0xC0000000u) >> 15;
    if (bin < NBIN) atomicAdd(&hist[bin], 1);
  }
  __syncthreads();

  int h0 = hist[2 * tid], h1 = hist[2 * tid + 1];
  int v = h0 + h1;
  int iv = v;
  #pragma unroll
  for (int d = 1; d < 64; d <<= 1) {
    int t = __shfl_up(iv, d);
    if (lane >= d) iv += t;
  }
  if (lane == 63) wsum[wid] = iv;
  __syncthreads();
  if (tid < 16) {
    int w = wsum[tid];
    #pragma unroll
    for (int d = 1; d < 16; d <<= 1) {
      int t = __shfl_up(w, d);
      if ((int)tid >= d) w += t;
    }
    wsum[tid] = w;
  }
  __syncthreads();
  int excl = iv - v + (wid > 0 ? wsum[wid - 1] : 0);
  hist[2 * tid] = excl + h0;
  hist[2 * tid + 1] = excl + h0 + h1;
  __syncthreads();

  int binLo = -1, cumBase = 0;
  for (int c = 0; c < NCHK; ++c) {
    if (tid == 0) sBinHi = binLo;
    __syncthreads();
    const int limit = cumBase + CH;
    int loc = -1;
    if (hist[2 * tid] <= limit) loc = 2 * tid;
    if (hist[2 * tid + 1] <= limit) loc = 2 * tid + 1;
    if (loc > binLo) atomicMax(&sBinHi, loc);
    __syncthreads();
    int binHi = sBinHi;
    if (binHi == binLo) binHi = binLo + 1;   // oversized-single-bin fallback
    if (2 * tid > binLo && 2 * tid <= binHi) chunkIdL[2 * tid] = c;
    if (2 * tid + 1 > binLo && 2 * tid + 1 <= binHi) chunkIdL[2 * tid + 1] = c;
    cumBase = hist[(binHi < NBIN ? binHi : NBIN - 1)];
    binLo = binHi;
    __syncthreads();
  }

  for (int i0 = 0; i0 < Nn; i0 += 1024) {
    int i = i0 + tid;
    int c = 255;
    if (i < Nn) {
      u32 kv = kb[i];
      u32 bin = (kv - 0xC0000000u) >> 15;
      if (bin < NBIN) c = chunkIdL[bin];
    }
    #pragma unroll
    for (int cc = 0; cc < NCHK; ++cc) {
      bool pred = (c == cc);
      u64 m = __ballot(pred);
      if (m) {
        int base = 0;
        if (lane == 0) base = atomicAdd(&sCnt[cc], (int)__popcll(m));
        base = __shfl(base, 0);
        if (pred) {
          int off = (int)__popcll(m & ((1ULL << lane) - 1ULL));
          int p = base + off;
          if (p < CH) clist[b * CHTOT + cc * CH + p] = i;
        }
      }
    }
  }
  __syncthreads();
  if (tid < NCHK) chunkCntG[b * NCHK + tid] = sCnt[tid];
}

// ============================================================
// y4: full-grid exact f64 rescore of chunks 0..1 FUSED with 256-element
// presort (verbatim R13)
// ============================================================
__global__ __launch_bounds__(256) void y4_rescore(const float* __restrict__ logits,
                                                  const float* __restrict__ anchors,
                                                  const int* __restrict__ clist,
                                                  const int* __restrict__ chunkCntG,
                                                  double* __restrict__ boxesd,
                                                  int* __restrict__ clsd,
                                                  u64* __restrict__ ekeysG) {
  __shared__ u64 ekseg[256];
  const int tid = threadIdx.x;
  const int bx = blockIdx.x;
  const int b = bx >> 4;
  const int blk = bx & 15;
  const int c = blk >> 3;                 // 0..1
  const int seg = blk & 7;                // 0..7
  int cnt = chunkCntG[b * NCHK + c];
  cnt = cnt > CH ? CH : cnt;
  const int g = tid >> 2, s = tid & 3;

  #pragma unroll 1
  for (int pass = 0; pass < 4; ++pass) {
    const int slot = seg * 256 + pass * 64 + g;
    u64 K = ~0ULL;
    if (slot < cnt) {
      const int n = clist[b * CHTOT + c * CH + slot];
      const float* row = logits + ((size_t)b * Nn + n) * 85;
      float rv[21];
      float mx = -1e30f; int ai = 1000;
      #pragma unroll
      for (int q = 0; q < 21; ++q) {
        int cc = s + 4 * q;
        float vv = (cc < 81) ? row[4 + cc] : -1e30f;
        rv[q] = vv;
        if (cc < 81 && vv > mx) { mx = vv; ai = cc; }
      }
      #pragma unroll
      for (int d = 1; d <= 2; d <<= 1) {
        float om = __shfl_xor(mx, d);
        int oi = __shfl_xor(ai, d);
        if (om > mx || (om == mx && oi < ai)) { mx = om; ai = oi; }
      }
      double sum = 0.0;
      #pragma unroll
      for (int q = 0; q < 21; ++q) {
        if (s + 4 * q < 81) sum += fast_exp_d((double)rv[q] - (double)mx);
      }
      sum += __shfl_xor(sum, 1);
      sum += __shfl_xor(sum, 2);
      if (s == 0) {
        double score = 1.0 / sum;
        if (ai != 0 && score >= 0.01) {
          float4 a4 = reinterpret_cast<const float4*>(anchors)[n];
          double ax1 = a4.x, ay1 = a4.y, ax2 = a4.z, ay2 = a4.w;
          double cx = (ax2 + ax1) * 0.5, cy = (ay2 + ay1) * 0.5;
          double ww = ax2 - ax1, hh = ay2 - ay1;
          double ctrx = (double)row[0] * ww + cx;
          double ctry = (double)row[1] * hh + cy;
          double szx = fast_exp_d((double)row[2]) * ww;
          double szy = fast_exp_d((double)row[3]) * hh;
          double* bp = boxesd + (size_t)(b * Nn + n) * 4;
          bp[0] = clip01(ctrx - szx * 0.5);
          bp[1] = clip01(ctry - szy * 0.5);
          bp[2] = clip01(ctrx + szx * 0.5);
          bp[3] = clip01(ctry + szy * 0.5);
          clsd[b * Nn + n] = ai;
          u64 sb2 = (u64)__double_as_longlong(score);
          u64 e4 = (sb2 >> 52) - 1015ULL;
          u64 mant45 = (sb2 & ((1ULL << 52) - 1)) >> 7;
          u64 flip = (~((e4 << 45) | mant45)) & ((1ULL << 49) - 1);
          K = (flip << 15) | (u64)n;
        }
      }
    }
    if (s == 0) ekseg[pass * 64 + g] = K;
  }
  __syncthreads();

  for (int k = 2; k <= 256; k <<= 1) {
    for (int j = k >> 1; j >= 1; j >>= 1) {
      if (tid < 128) {
        int l = ((tid & ~(j - 1)) << 1) | (tid & (j - 1));
        int r = l | j;
        bool up = ((l & k) == 0);
        u64 a = ekseg[l], bv = ekseg[r];
        if ((a > bv) == up) { ekseg[l] = bv; ekseg[r] = a; }
      }
      __syncthreads();
    }
  }
  u64* dstp = ekeysG + (size_t)b * CHPRE + c * CH + seg * 256;
  for (int i = tid; i < 256; i += 256) dstp[i] = ekseg[i];
}

// ============================================================
// y5: per-image: chunk loop {8-way bitonic merge (c<2) or inline
// rescore + full sort (c>=2) -> multi-wave NMS} -> outputs (verbatim R13)
// ============================================================
__global__ __launch_bounds__(1024) void y5_sortnms(const float* __restrict__ logits,
                                                   const float* __restrict__ anchors,
                                                   const u64* __restrict__ ekeysG,
                                                   const int* __restrict__ chunkCntG,
                                                   const int* __restrict__ clist,
                                                   double* __restrict__ boxesd,
                                                   int* __restrict__ clsd,
                                                   float* __restrict__ out) {
  __shared__ u64 ek[CH];
  __shared__ double bbuf[2][64][4];
  __shared__ u64 awv[16];
  __shared__ u64 killm[64];
  __shared__ double selBox[MAXB][4];
  __shared__ double selArea[MAXB];
  __shared__ float selScore[MAXB];
  __shared__ int selIdx[MAXB];
  __shared__ int sS;
  const int b = blockIdx.x;
  const int tid = threadIdx.x;
  const int lane = tid & 63, wid = tid >> 6;
  const double THR = 0.45;
  if (tid == 0) sS = 0;
  __syncthreads();

  for (int c = 0; c < NCHK; ++c) {
    if (sS >= MAXB) break;
    int cnt = chunkCntG[b * NCHK + c];
    cnt = cnt > CH ? CH : cnt;
    if (cnt == 0) break;

    if (c < CHK_PRE) {
      for (int i = tid; i < CH; i += 1024) ek[i] = ekeysG[(size_t)b * CHPRE + c * CH + i];
      __syncthreads();
      for (int L = 256; L <= 1024; L <<= 1) {
        int pair = tid / L, i = tid % L;
        int base = pair * 2 * L;
        int l = base + i, r = base + 2 * L - 1 - i;
        u64 a = ek[l], bv = ek[r];
        if (a > bv) { ek[l] = bv; ek[r] = a; }
        __syncthreads();
        for (int j = L >> 1; j >= 1; j >>= 1) {
          int ll = ((tid & ~(j - 1)) << 1) | (tid & (j - 1));
          int rr = ll | j;
          u64 x = ek[ll], y = ek[rr];
          if (x > y) { ek[ll] = y; ek[rr] = x; }
          __syncthreads();
        }
      }
    } else {
      for (int i = tid; i < CH; i += 1024) ek[i] = ~0ULL;
      __syncthreads();
      const int g = tid >> 2, s4 = tid & 3;
      #pragma unroll 1
      for (int pass = 0; pass < CH / 256; ++pass) {
        int slot = pass * 256 + g;
        if (slot < cnt) {
          const int n = clist[b * CHTOT + c * CH + slot];
          const float* row = logits + ((size_t)b * Nn + n) * 85;
          float rv[21];
          float mx = -1e30f; int ai = 1000;
          #pragma unroll
          for (int q = 0; q < 21; ++q) {
            int cc = s4 + 4 * q;
            float vv = (cc < 81) ? row[4 + cc] : -1e30f;
            rv[q] = vv;
            if (cc < 81 && vv > mx) { mx = vv; ai = cc; }
          }
          #pragma unroll
          for (int d = 1; d <= 2; d <<= 1) {
            float om = __shfl_xor(mx, d);
            int oi = __shfl_xor(ai, d);
            if (om > mx || (om == mx && oi < ai)) { mx = om; ai = oi; }
          }
          double sum = 0.0;
          #pragma unroll
          for (int q = 0; q < 21; ++q) {
            if (s4 + 4 * q < 81) sum += fast_exp_d((double)rv[q] - (double)mx);
          }
          sum += __shfl_xor(sum, 1);
          sum += __shfl_xor(sum, 2);
          if (s4 == 0) {
            u64 K = ~0ULL;
            double score = 1.0 / sum;
            if (ai != 0 && score >= 0.01) {
              float4 a4 = reinterpret_cast<const float4*>(anchors)[n];
              double ax1 = a4.x, ay1 = a4.y, ax2 = a4.z, ay2 = a4.w;
              double cx = (ax2 + ax1) * 0.5, cy = (ay2 + ay1) * 0.5;
              double ww = ax2 - ax1, hh = ay2 - ay1;
              double ctrx = (double)row[0] * ww + cx;
              double ctry = (double)row[1] * hh + cy;
              double szx = fast_exp_d((double)row[2]) * ww;
              double szy = fast_exp_d((double)row[3]) * hh;
              double* bp = boxesd + (size_t)(b * Nn + n) * 4;
              bp[0] = clip01(ctrx - szx * 0.5);
              bp[1] = clip01(ctry - szy * 0.5);
              bp[2] = clip01(ctrx + szx * 0.5);
              bp[3] = clip01(ctry + szy * 0.5);
              clsd[b * Nn + n] = ai;
              u64 sb2 = (u64)__double_as_longlong(score);
              u64 e4 = (sb2 >> 52) - 1015ULL;
              u64 mant45 = (sb2 & ((1ULL << 52) - 1)) >> 7;
              u64 flip = (~((e4 << 45) | mant45)) & ((1ULL << 49) - 1);
              K = (flip << 15) | (u64)n;
            }
            ek[slot] = K;
          }
        }
      }
      __syncthreads();
      int P2 = 64;
      while (P2 < cnt) P2 <<= 1;
      for (int k = 2; k <= P2; k <<= 1) {
        for (int j = k >> 1; j >= 1; j >>= 1) {
          if (tid < (P2 >> 1)) {
            int l = ((tid & ~(j - 1)) << 1) | (tid & (j - 1));
            int r = l | j;
            bool up = ((l & k) == 0);
            u64 a = ek[l], bbv = ek[r];
            if ((a > bbv) == up) { ek[l] = bbv; ek[r] = a; }
          }
          __syncthreads();
        }
      }
    }

    // ---- multi-wave NMS, parallel kill-masks ----
    int pos = 0, bf = 0;
    if (tid < 256) {
      int ci = tid >> 2, comp = tid & 3;
      u64 Kc = ek[ci];
      double vv = 0.0;
      if (Kc != ~0ULL) vv = boxesd[(size_t)(b * Nn + (int)(Kc & 0x7FFF)) * 4 + comp];
      bbuf[0][ci][comp] = vv;
    }
    __syncthreads();
    for (;;) {
      int S = sS;
      if (S >= MAXB || pos >= CH) break;
      u64 K = ek[pos + lane];
      bool valid = (K != ~0ULL);
      if (!__any(valid)) break;

      if (tid < 256 && pos + 64 < CH) {
        int ci = tid >> 2, comp = tid & 3;
        u64 Kc = ek[pos + 64 + ci];
        double vv = 0.0;
        if (Kc != ~0ULL) vv = boxesd[(size_t)(b * Nn + (int)(Kc & 0x7FFF)) * 4 + comp];
        bbuf[bf ^ 1][ci][comp] = vv;
      }

      double cx1 = bbuf[bf][lane][0], cy1 = bbuf[bf][lane][1];
      double cx2 = bbuf[bf][lane][2], cy2 = bbuf[bf][lane][3];
      double carea = (cx2 - cx1) * (cy2 - cy1);

      bool aliveL = true;
      for (int k = wid; k < S; k += 16) {
        double ltx = fmax(selBox[k][0], cx1), lty = fmax(selBox[k][1], cy1);
        double rbx = fmin(selBox[k][2], cx2), rby = fmin(selBox[k][3], cy2);
        double w = rbx - ltx; w = w < 0 ? 0 : w;
        double h = rby - lty; h = h < 0 ? 0 : h;
        double inter = w * h;
        double denom = selArea[k] + carea - inter + 1e-9;
        if (inter > THR * denom) aliveL = false;
      }
      u64 aw = __ballot(aliveL);
      if (lane == 0) awv[wid] = aw;

      #pragma unroll
      for (int q = 0; q < 4; ++q) {
        int j = (wid << 2) | q;
        double jx1 = bbuf[bf][j][0], jy1 = bbuf[bf][j][1];
        double jx2 = bbuf[bf][j][2], jy2 = bbuf[bf][j][3];
        double jar = (jx2 - jx1) * (jy2 - jy1);
        double ltx = fmax(jx1, cx1), lty = fmax(jy1, cy1);
        double rbx = fmin(jx2, cx2), rby = fmin(jy2, cy2);
        double w = rbx - ltx; w = w < 0 ? 0 : w;
        double h = rby - lty; h = h < 0 ? 0 : h;
        double inter = w * h;
        double denom = jar + carea - inter + 1e-9;
        u64 km = __ballot(inter > THR * denom);
        if (lane == 0) killm[j] = km;
      }
      __syncthreads();

      if (tid < 64) {
        u64 alive = __ballot(valid);
        #pragma unroll
        for (int w = 0; w < 16; ++w) alive &= awv[w];
        u64 m = alive;
        int Sl = S;
        while (m != 0 && Sl < MAXB) {
          int j = __ffsll((unsigned long long)m) - 1;
          if (lane == 0) {
            double jx1 = bbuf[bf][j][0], jy1 = bbuf[bf][j][1];
            double jx2 = bbuf[bf][j][2], jy2 = bbuf[bf][j][3];
            u64 Kj = ek[pos + j];
            u64 key49 = (~(Kj >> 15)) & ((1ULL << 49) - 1);
            u64 e = (key49 >> 45) + 1015ULL;
            u64 mant = (key49 & ((1ULL << 45) - 1)) << 7;
            selBox[Sl][0] = jx1; selBox[Sl][1] = jy1;
            selBox[Sl][2] = jx2; selBox[Sl][3] = jy2;
            selArea[Sl] = (jx2 - jx1) * (jy2 - jy1);
            selScore[Sl] = (float)__longlong_as_double((long long)((e << 52) | mant));
            selIdx[Sl] = (int)(Kj & 0x7FFF);
          }
          Sl++;
          m &= ~(1ULL << j);
          m &= ~killm[j];
        }
        if (lane == 0) sS = Sl;
      }
      __syncthreads();
      bf ^= 1;
      pos += 64;
    }
    __syncthreads();
  }

  // --- outputs (whole buffer read as f32 by harness) ---
  const int S = sS;
  float* det_boxes = out;
  float* det_classes = out + Bn * MAXB * 4;
  float* det_scores = out + Bn * MAXB * 4 + Bn * MAXB;
  float* det_num = out + Bn * MAXB * 4 + 2 * Bn * MAXB;
  for (int k = tid; k < MAXB; k += 1024) {
    int o = b * MAXB + k;
    if (k < S) {
      det_boxes[o * 4 + 0] = (float)selBox[k][0];
      det_boxes[o * 4 + 1] = (float)selBox[k][1];
      det_boxes[o * 4 + 2] = (float)selBox[k][2];
      det_boxes[o * 4 + 3] = (float)selBox[k][3];
      det_classes[o] = (float)clsd[b * Nn + selIdx[k]];
      det_scores[o] = selScore[k];
    } else {
      det_boxes[o * 4 + 0] = 0.f; det_boxes[o * 4 + 1] = 0.f;
      det_boxes[o * 4 + 2] = 0.f; det_boxes[o * 4 + 3] = 0.f;
      det_classes[o] = 0.f;
      det_scores[o] = 0.f;
    }
  }
  if (tid == 0) det_num[b] = (float)S;
}

// ============================================================
extern "C" void kernel_launch(void* const* d_in, const int* in_sizes, int n_in,
                              void* d_out, int out_size, void* d_ws, size_t ws_size,
                              hipStream_t stream) {
  const float* logits = (const float*)d_in[0];
  const float* anchors = (const float*)d_in[1];
  float* out = (float*)d_out;
  char* ws = (char*)d_ws;

  double* boxesd = (double*)ws;
  size_t off = (size_t)Bn * Nn * 4 * sizeof(double);
  int* clsd    = (int*)(ws + off);  off += (size_t)Bn * Nn * sizeof(int);
  u32* keyA    = (u32*)(ws + off);  off += (size_t)Bn * Nn * sizeof(u32);
  int* chunkCnt= (int*)(ws + off);  off += (size_t)Bn * NCHK * sizeof(int);
  int* clist   = (int*)(ws + off);  off += (size_t)Bn * CHTOT * sizeof(int);
  u64* ekeysG  = (u64*)(ws + off);

  y1_score     <<<dim3(Bn * 384), dim3(256),  0, stream>>>(logits, keyA);
  y3_cutcompact<<<dim3(Bn),       dim3(1024), 0, stream>>>(keyA, chunkCnt, clist);
  y4_rescore   <<<dim3(Bn * 16),  dim3(256),  0, stream>>>(logits, anchors, clist, chunkCnt,
                                                           boxesd, clsd, ekeysG);
  y5_sortnms   <<<dim3(Bn),       dim3(1024), 0, stream>>>(logits, anchors, ekeysG, chunkCnt,
                                                           clist, boxesd, clsd, out);
}

// Round 15
// 154.385 us; speedup vs baseline: 1.3405x; 1.0067x over previous
//
#include <hip/hip_runtime.h>

#define Bn 32
#define Nn 24564
#define MAXB 200
#define NBIN 2048
#define CH 2048
#define NCHK 4
#define CHK_PRE 3
#define CHTOT (NCHK * CH)
#define CHPRE (CHK_PRE * CH)
#define INVK 0xFFFFFFFFu
#define NITER 24

typedef unsigned long long u64;
typedef unsigned int u32;

// -------- accurate double exp (rel err ~6e-15) -- bit-stable since R2 --------
__device__ inline double fast_exp_d(double x) {
  const double LOG2E = 1.4426950408889634074;
  const double LN2   = 0.69314718055994530942;
  double t = x * LOG2E;
  double fi = floor(t + 0.5);
  double f = (t - fi) * LN2;
  double p = 2.505210838544172e-8;
  p = p * f + 2.755731922398589e-7;
  p = p * f + 2.7557319223985893e-6;
  p = p * f + 2.48015873015873e-5;
  p = p * f + 1.984126984126984e-4;
  p = p * f + 1.3888888888888889e-3;
  p = p * f + 8.333333333333333e-3;
  p = p * f + 4.1666666666666664e-2;
  p = p * f + 1.6666666666666666e-1;
  p = p * f + 0.5;
  p = p * f + 1.0;
  p = p * f + 1.0;
  long long e = (long long)fi;
  return p * __longlong_as_double((e + 1023LL) << 52);
}

__device__ inline double clip01(double v) {
  return v < 0.0 ? 0.0 : (v > 1.0 ? 1.0 : v);
}

// ============================================================
// z1: f32 scoring, direct global loads (R14-proven, ~38us, HBM roofline)
// ============================================================
__global__ __launch_bounds__(256) void z1_score(const float* __restrict__ logits,
                                                u32* __restrict__ keyA) {
  const int tid = threadIdx.x;
  const int bx = blockIdx.x;
  const int b = bx / 384;
  const int n0 = (bx % 384) << 6;
  const int g = tid >> 2, s = tid & 3;
  const int n = n0 + g;
  if (n >= Nn) return;
  const float* row = logits + ((size_t)b * Nn + n) * 85;

  float rv[21];
  float mx = -1e30f; int ai = 1000;
  #pragma unroll
  for (int q = 0; q < 21; ++q) {
    int c = s + 4 * q;
    float v = (c < 81) ? row[4 + c] : -1e30f;
    rv[q] = v;
    if (c < 81 && v > mx) { mx = v; ai = c; }
  }
  #pragma unroll
  for (int d = 1; d <= 2; d <<= 1) {
    float om = __shfl_xor(mx, d);
    int oi = __shfl_xor(ai, d);
    if (om > mx || (om == mx && oi < ai)) { mx = om; ai = oi; }
  }
  float sum = 0.f;
  #pragma unroll
  for (int q = 0; q < 21; ++q) {
    if (s + 4 * q < 81) sum += __expf(rv[q] - mx);
  }
  sum += __shfl_xor(sum, 1);
  sum += __shfl_xor(sum, 2);
  if (s == 0) {
    float sc = 1.0f / sum;
    u32 kv = INVK;
    if (ai != 0 && sc >= 0.00985f) kv = ~__float_as_uint(sc);  // margin; exact recheck later
    keyA[(size_t)b * Nn + n] = kv;
  }
}

// ============================================================
// z3: per-image cut+compact with REGISTER-PREFETCHED keys:
// all 24 keys/thread loaded up front (latency overlapped), hist from
// registers, compact reuses the same registers (no 2nd global read).
// Index order per thread identical to R12-14 -> bit-identical results.
// ============================================================
__global__ __launch_bounds__(1024) void z3_cutcompact(const u32* __restrict__ keyA,
                                                      int* __restrict__ chunkCntG,
                                                      int* __restrict__ clist) {
  __shared__ int hist[NBIN];
  __shared__ int chunkIdL[NBIN];
  __shared__ int wsum[16];
  __shared__ int sBinHi;
  __shared__ int sCnt[NCHK];
  const int b = blockIdx.x;
  const int tid = threadIdx.x;
  const int lane = tid & 63, wid = tid >> 6;
  const u32* kb = keyA + (size_t)b * Nn;

  // prefetch all keys for this thread (independent loads, deep in flight)
  u32 kvreg[NITER];
  #pragma unroll
  for (int it = 0; it < NITER; ++it) {
    int i = it * 1024 + tid;
    kvreg[it] = (i < Nn) ? kb[i] : INVK;
  }

  for (int i = tid; i < NBIN; i += 1024) hist[i] = 0;
  chunkIdL[2 * tid] = 255;
  chunkIdL[2 * tid + 1] = 255;
  if (tid < NCHK) sCnt[tid] = 0;
  __syncthreads();

  #pragma unroll
  for (int it = 0; it < NITER; ++it) {
    u32 bin = (kvreg[it] - 0xC0000000u) >> 15;   // INVK -> huge (skipped)
    if (bin < NBIN) atomicAdd(&hist[bin], 1);
  }
  __syncthreads();

  // inclusive prefix scan (proven R6 code)
  int h0 = hist[2 * tid], h1 = hist[2 * tid + 1];
  int v = h0 + h1;
  int iv = v;
  #pragma unroll
  for (int d = 1; d < 64; d <<= 1) {
    int t = __shfl_up(iv, d);
    if (lane >= d) iv += t;
  }
  if (lane == 63) wsum[wid] = iv;
  __syncthreads();
  if (tid < 16) {
    int w = wsum[tid];
    #pragma unroll
    for (int d = 1; d < 16; d <<= 1) {
      int t = __shfl_up(w, d);
      if ((int)tid >= d) w += t;
    }
    wsum[tid] = w;
  }
  __syncthreads();
  int excl = iv - v + (wid > 0 ? wsum[wid - 1] : 0);
  hist[2 * tid] = excl + h0;
  hist[2 * tid + 1] = excl + h0 + h1;
  __syncthreads();

  // chunk boundaries (proven R8 loop)
  int binLo = -1, cumBase = 0;
  for (int c = 0; c < NCHK; ++c) {
    if (tid == 0) sBinHi = binLo;
    __syncthreads();
    const int limit = cumBase + CH;
    int loc = -1;
    if (hist[2 * tid] <= limit) loc = 2 * tid;
    if (hist[2 * tid + 1] <= limit) loc = 2 * tid + 1;
    if (loc > binLo) atomicMax(&sBinHi, loc);
    __syncthreads();
    int binHi = sBinHi;
    if (binHi == binLo) binHi = binLo + 1;   // oversized-single-bin fallback
    if (2 * tid > binLo && 2 * tid <= binHi) chunkIdL[2 * tid] = c;
    if (2 * tid + 1 > binLo && 2 * tid + 1 <= binHi) chunkIdL[2 * tid + 1] = c;
    cumBase = hist[(binHi < NBIN ? binHi : NBIN - 1)];
    binLo = binHi;
    __syncthreads();
  }

  // compaction from registers (LDS counters, wave-aggregated)
  #pragma unroll 1
  for (int it = 0; it < NITER; ++it) {
    int i = it * 1024 + tid;
    int c = 255;
    u32 bin = (kvreg[it] - 0xC0000000u) >> 15;
    if (i < Nn && bin < NBIN) c = chunkIdL[bin];
    #pragma unroll
    for (int cc = 0; cc < NCHK; ++cc) {
      bool pred = (c == cc);
      u64 m = __ballot(pred);
      if (m) {
        int base = 0;
        if (lane == 0) base = atomicAdd(&sCnt[cc], (int)__popcll(m));
        base = __shfl(base, 0);
        if (pred) {
          int off = (int)__popcll(m & ((1ULL << lane) - 1ULL));
          int p = base + off;
          if (p < CH) clist[b * CHTOT + cc * CH + p] = i;
        }
      }
    }
  }
  __syncthreads();
  if (tid < NCHK) chunkCntG[b * NCHK + tid] = sCnt[tid];
}

// ============================================================
// z4: full-grid exact f64 rescore of chunks 0..2 FUSED with 256-presort
// (formulas/order verbatim R13; CHK_PRE now 3)
// ============================================================
__global__ __launch_bounds__(256) void z4_rescore(const float* __restrict__ logits,
                                                  const float* __restrict__ anchors,
                                                  const int* __restrict__ clist,
                                                  const int* __restrict__ chunkCntG,
                                                  double* __restrict__ boxesd,
                                                  int* __restrict__ clsd,
                                                  u64* __restrict__ ekeysG) {
  __shared__ u64 ekseg[256];
  const int tid = threadIdx.x;
  const int bx = blockIdx.x;
  const int b = bx / (CHK_PRE * 8);
  const int blk = bx % (CHK_PRE * 8);
  const int c = blk >> 3;                 // 0..CHK_PRE-1
  const int seg = blk & 7;                // 0..7
  int cnt = chunkCntG[b * NCHK + c];
  cnt = cnt > CH ? CH : cnt;
  const int g = tid >> 2, s = tid & 3;

  #pragma unroll 1
  for (int pass = 0; pass < 4; ++pass) {
    const int slot = seg * 256 + pass * 64 + g;
    u64 K = ~0ULL;
    if (slot < cnt) {
      const int n = clist[b * CHTOT + c * CH + slot];
      const float* row = logits + ((size_t)b * Nn + n) * 85;
      float rv[21];
      float mx = -1e30f; int ai = 1000;
      #pragma unroll
      for (int q = 0; q < 21; ++q) {
        int cc = s + 4 * q;
        float vv = (cc < 81) ? row[4 + cc] : -1e30f;
        rv[q] = vv;
        if (cc < 81 && vv > mx) { mx = vv; ai = cc; }
      }
      #pragma unroll
      for (int d = 1; d <= 2; d <<= 1) {
        float om = __shfl_xor(mx, d);
        int oi = __shfl_xor(ai, d);
        if (om > mx || (om == mx && oi < ai)) { mx = om; ai = oi; }
      }
      double sum = 0.0;
      #pragma unroll
      for (int q = 0; q < 21; ++q) {
        if (s + 4 * q < 81) sum += fast_exp_d((double)rv[q] - (double)mx);
      }
      sum += __shfl_xor(sum, 1);
      sum += __shfl_xor(sum, 2);
      if (s == 0) {
        double score = 1.0 / sum;
        if (ai != 0 && score >= 0.01) {
          float4 a4 = reinterpret_cast<const float4*>(anchors)[n];
          double ax1 = a4.x, ay1 = a4.y, ax2 = a4.z, ay2 = a4.w;
          double cx = (ax2 + ax1) * 0.5, cy = (ay2 + ay1) * 0.5;
          double ww = ax2 - ax1, hh = ay2 - ay1;
          double ctrx = (double)row[0] * ww + cx;
          double ctry = (double)row[1] * hh + cy;
          double szx = fast_exp_d((double)row[2]) * ww;
          double szy = fast_exp_d((double)row[3]) * hh;
          double* bp = boxesd + (size_t)(b * Nn + n) * 4;
          bp[0] = clip01(ctrx - szx * 0.5);
          bp[1] = clip01(ctry - szy * 0.5);
          bp[2] = clip01(ctrx + szx * 0.5);
          bp[3] = clip01(ctry + szy * 0.5);
          clsd[b * Nn + n] = ai;
          u64 sb2 = (u64)__double_as_longlong(score);
          u64 e4 = (sb2 >> 52) - 1015ULL;
          u64 mant45 = (sb2 & ((1ULL << 52) - 1)) >> 7;
          u64 flip = (~((e4 << 45) | mant45)) & ((1ULL << 49) - 1);
          K = (flip << 15) | (u64)n;
        }
      }
    }
    if (s == 0) ekseg[pass * 64 + g] = K;
  }
  __syncthreads();

  for (int k = 2; k <= 256; k <<= 1) {
    for (int j = k >> 1; j >= 1; j >>= 1) {
      if (tid < 128) {
        int l = ((tid & ~(j - 1)) << 1) | (tid & (j - 1));
        int r = l | j;
        bool up = ((l & k) == 0);
        u64 a = ekseg[l], bv = ekseg[r];
        if ((a > bv) == up) { ekseg[l] = bv; ekseg[r] = a; }
      }
      __syncthreads();
    }
  }
  u64* dstp = ekeysG + (size_t)b * CHPRE + c * CH + seg * 256;
  for (int i = tid; i < 256; i += 256) dstp[i] = ekseg[i];
}

// ============================================================
// z5: per-image: chunk loop {8-way bitonic merge (c<3) or inline
// rescore + full sort (c==3, ~never) -> multi-wave NMS} -> outputs
// ============================================================
__global__ __launch_bounds__(1024) void z5_sortnms(const float* __restrict__ logits,
                                                   const float* __restrict__ anchors,
                                                   const u64* __restrict__ ekeysG,
                                                   const int* __restrict__ chunkCntG,
                                                   const int* __restrict__ clist,
                                                   double* __restrict__ boxesd,
                                                   int* __restrict__ clsd,
                                                   float* __restrict__ out) {
  __shared__ u64 ek[CH];
  __shared__ double bbuf[2][64][4];
  __shared__ u64 awv[16];
  __shared__ u64 killm[64];
  __shared__ double selBox[MAXB][4];
  __shared__ double selArea[MAXB];
  __shared__ float selScore[MAXB];
  __shared__ int selIdx[MAXB];
  __shared__ int sS;
  const int b = blockIdx.x;
  const int tid = threadIdx.x;
  const int lane = tid & 63, wid = tid >> 6;
  const double THR = 0.45;
  if (tid == 0) sS = 0;
  __syncthreads();

  for (int c = 0; c < NCHK; ++c) {
    if (sS >= MAXB) break;
    int cnt = chunkCntG[b * NCHK + c];
    cnt = cnt > CH ? CH : cnt;
    if (cnt == 0) break;

    if (c < CHK_PRE) {
      for (int i = tid; i < CH; i += 1024) ek[i] = ekeysG[(size_t)b * CHPRE + c * CH + i];
      __syncthreads();
      for (int L = 256; L <= 1024; L <<= 1) {
        int pair = tid / L, i = tid % L;
        int base = pair * 2 * L;
        int l = base + i, r = base + 2 * L - 1 - i;
        u64 a = ek[l], bv = ek[r];
        if (a > bv) { ek[l] = bv; ek[r] = a; }
        __syncthreads();
        for (int j = L >> 1; j >= 1; j >>= 1) {
          int ll = ((tid & ~(j - 1)) << 1) | (tid & (j - 1));
          int rr = ll | j;
          u64 x = ek[ll], y = ek[rr];
          if (x > y) { ek[ll] = y; ek[rr] = x; }
          __syncthreads();
        }
      }
    } else {
      for (int i = tid; i < CH; i += 1024) ek[i] = ~0ULL;
      __syncthreads();
      const int g = tid >> 2, s4 = tid & 3;
      #pragma unroll 1
      for (int pass = 0; pass < CH / 256; ++pass) {
        int slot = pass * 256 + g;
        if (slot < cnt) {
          const int n = clist[b * CHTOT + c * CH + slot];
          const float* row = logits + ((size_t)b * Nn + n) * 85;
          float rv[21];
          float mx = -1e30f; int ai = 1000;
          #pragma unroll
          for (int q = 0; q < 21; ++q) {
            int cc = s4 + 4 * q;
            float vv = (cc < 81) ? row[4 + cc] : -1e30f;
            rv[q] = vv;
            if (cc < 81 && vv > mx) { mx = vv; ai = cc; }
          }
          #pragma unroll
          for (int d = 1; d <= 2; d <<= 1) {
            float om = __shfl_xor(mx, d);
            int oi = __shfl_xor(ai, d);
            if (om > mx || (om == mx && oi < ai)) { mx = om; ai = oi; }
          }
          double sum = 0.0;
          #pragma unroll
          for (int q = 0; q < 21; ++q) {
            if (s4 + 4 * q < 81) sum += fast_exp_d((double)rv[q] - (double)mx);
          }
          sum += __shfl_xor(sum, 1);
          sum += __shfl_xor(sum, 2);
          if (s4 == 0) {
            u64 K = ~0ULL;
            double score = 1.0 / sum;
            if (ai != 0 && score >= 0.01) {
              float4 a4 = reinterpret_cast<const float4*>(anchors)[n];
              double ax1 = a4.x, ay1 = a4.y, ax2 = a4.z, ay2 = a4.w;
              double cx = (ax2 + ax1) * 0.5, cy = (ay2 + ay1) * 0.5;
              double ww = ax2 - ax1, hh = ay2 - ay1;
              double ctrx = (double)row[0] * ww + cx;
              double ctry = (double)row[1] * hh + cy;
              double szx = fast_exp_d((double)row[2]) * ww;
              double szy = fast_exp_d((double)row[3]) * hh;
              double* bp = boxesd + (size_t)(b * Nn + n) * 4;
              bp[0] = clip01(ctrx - szx * 0.5);
              bp[1] = clip01(ctry - szy * 0.5);
              bp[2] = clip01(ctrx + szx * 0.5);
              bp[3] = clip01(ctry + szy * 0.5);
              clsd[b * Nn + n] = ai;
              u64 sb2 = (u64)__double_as_longlong(score);
              u64 e4 = (sb2 >> 52) - 1015ULL;
              u64 mant45 = (sb2 & ((1ULL << 52) - 1)) >> 7;
              u64 flip = (~((e4 << 45) | mant45)) & ((1ULL << 49) - 1);
              K = (flip << 15) | (u64)n;
            }
            ek[slot] = K;
          }
        }
      }
      __syncthreads();
      int P2 = 64;
      while (P2 < cnt) P2 <<= 1;
      for (int k = 2; k <= P2; k <<= 1) {
        for (int j = k >> 1; j >= 1; j >>= 1) {
          if (tid < (P2 >> 1)) {
            int l = ((tid & ~(j - 1)) << 1) | (tid & (j - 1));
            int r = l | j;
            bool up = ((l & k) == 0);
            u64 a = ek[l], bbv = ek[r];
            if ((a > bbv) == up) { ek[l] = bbv; ek[r] = a; }
          }
          __syncthreads();
        }
      }
    }

    // ---- multi-wave NMS, parallel kill-masks ----
    int pos = 0, bf = 0;
    if (tid < 256) {
      int ci = tid >> 2, comp = tid & 3;
      u64 Kc = ek[ci];
      double vv = 0.0;
      if (Kc != ~0ULL) vv = boxesd[(size_t)(b * Nn + (int)(Kc & 0x7FFF)) * 4 + comp];
      bbuf[0][ci][comp] = vv;
    }
    __syncthreads();
    for (;;) {
      int S = sS;
      if (S >= MAXB || pos >= CH) break;
      u64 K = ek[pos + lane];
      bool valid = (K != ~0ULL);
      if (!__any(valid)) break;

      if (tid < 256 && pos + 64 < CH) {
        int ci = tid >> 2, comp = tid & 3;
        u64 Kc = ek[pos + 64 + ci];
        double vv = 0.0;
        if (Kc != ~0ULL) vv = boxesd[(size_t)(b * Nn + (int)(Kc & 0x7FFF)) * 4 + comp];
        bbuf[bf ^ 1][ci][comp] = vv;
      }

      double cx1 = bbuf[bf][lane][0], cy1 = bbuf[bf][lane][1];
      double cx2 = bbuf[bf][lane][2], cy2 = bbuf[bf][lane][3];
      double carea = (cx2 - cx1) * (cy2 - cy1);

      bool aliveL = true;
      for (int k = wid; k < S; k += 16) {
        double ltx = fmax(selBox[k][0], cx1), lty = fmax(selBox[k][1], cy1);
        double rbx = fmin(selBox[k][2], cx2), rby = fmin(selBox[k][3], cy2);
        double w = rbx - ltx; w = w < 0 ? 0 : w;
        double h = rby - lty; h = h < 0 ? 0 : h;
        double inter = w * h;
        double denom = selArea[k] + carea - inter + 1e-9;
        if (inter > THR * denom) aliveL = false;
      }
      u64 aw = __ballot(aliveL);
      if (lane == 0) awv[wid] = aw;

      #pragma unroll
      for (int q = 0; q < 4; ++q) {
        int j = (wid << 2) | q;
        double jx1 = bbuf[bf][j][0], jy1 = bbuf[bf][j][1];
        double jx2 = bbuf[bf][j][2], jy2 = bbuf[bf][j][3];
        double jar = (jx2 - jx1) * (jy2 - jy1);
        double ltx = fmax(jx1, cx1), lty = fmax(jy1, cy1);
        double rbx = fmin(jx2, cx2), rby = fmin(jy2, cy2);
        double w = rbx - ltx; w = w < 0 ? 0 : w;
        double h = rby - lty; h = h < 0 ? 0 : h;
        double inter = w * h;
        double denom = jar + carea - inter + 1e-9;
        u64 km = __ballot(inter > THR * denom);
        if (lane == 0) killm[j] = km;
      }
      __syncthreads();

      if (tid < 64) {
        u64 alive = __ballot(valid);
        #pragma unroll
        for (int w = 0; w < 16; ++w) alive &= awv[w];
        u64 m = alive;
        int Sl = S;
        while (m != 0 && Sl < MAXB) {
          int j = __ffsll((unsigned long long)m) - 1;
          if (lane == 0) {
            double jx1 = bbuf[bf][j][0], jy1 = bbuf[bf][j][1];
            double jx2 = bbuf[bf][j][2], jy2 = bbuf[bf][j][3];
            u64 Kj = ek[pos + j];
            u64 key49 = (~(Kj >> 15)) & ((1ULL << 49) - 1);
            u64 e = (key49 >> 45) + 1015ULL;
            u64 mant = (key49 & ((1ULL << 45) - 1)) << 7;
            selBox[Sl][0] = jx1; selBox[Sl][1] = jy1;
            selBox[Sl][2] = jx2; selBox[Sl][3] = jy2;
            selArea[Sl] = (jx2 - jx1) * (jy2 - jy1);
            selScore[Sl] = (float)__longlong_as_double((long long)((e << 52) | mant));
            selIdx[Sl] = (int)(Kj & 0x7FFF);
          }
          Sl++;
          m &= ~(1ULL << j);
          m &= ~killm[j];
        }
        if (lane == 0) sS = Sl;
      }
      __syncthreads();
      bf ^= 1;
      pos += 64;
    }
    __syncthreads();
  }

  // --- outputs (whole buffer read as f32 by harness) ---
  const int S = sS;
  float* det_boxes = out;
  float* det_classes = out + Bn * MAXB * 4;
  float* det_scores = out + Bn * MAXB * 4 + Bn * MAXB;
  float* det_num = out + Bn * MAXB * 4 + 2 * Bn * MAXB;
  for (int k = tid; k < MAXB; k += 1024) {
    int o = b * MAXB + k;
    if (k < S) {
      det_boxes[o * 4 + 0] = (float)selBox[k][0];
      det_boxes[o * 4 + 1] = (float)selBox[k][1];
      det_boxes[o * 4 + 2] = (float)selBox[k][2];
      det_boxes[o * 4 + 3] = (float)selBox[k][3];
      det_classes[o] = (float)clsd[b * Nn + selIdx[k]];
      det_scores[o] = selScore[k];
    } else {
      det_boxes[o * 4 + 0] = 0.f; det_boxes[o * 4 + 1] = 0.f;
      det_boxes[o * 4 + 2] = 0.f; det_boxes[o * 4 + 3] = 0.f;
      det_classes[o] = 0.f;
      det_scores[o] = 0.f;
    }
  }
  if (tid == 0) det_num[b] = (float)S;
}

// ============================================================
extern "C" void kernel_launch(void* const* d_in, const int* in_sizes, int n_in,
                              void* d_out, int out_size, void* d_ws, size_t ws_size,
                              hipStream_t stream) {
  const float* logits = (const float*)d_in[0];
  const float* anchors = (const float*)d_in[1];
  float* out = (float*)d_out;
  char* ws = (char*)d_ws;

  double* boxesd = (double*)ws;
  size_t off = (size_t)Bn * Nn * 4 * sizeof(double);
  int* clsd    = (int*)(ws + off);  off += (size_t)Bn * Nn * sizeof(int);
  u32* keyA    = (u32*)(ws + off);  off += (size_t)Bn * Nn * sizeof(u32);
  int* chunkCnt= (int*)(ws + off);  off += (size_t)Bn * NCHK * sizeof(int);
  int* clist   = (int*)(ws + off);  off += (size_t)Bn * CHTOT * sizeof(int);
  u64* ekeysG  = (u64*)(ws + off);

  z1_score     <<<dim3(Bn * 384),        dim3(256),  0, stream>>>(logits, keyA);
  z3_cutcompact<<<dim3(Bn),              dim3(1024), 0, stream>>>(keyA, chunkCnt, clist);
  z4_rescore   <<<dim3(Bn * CHK_PRE * 8),dim3(256),  0, stream>>>(logits, anchors, clist,
                                                                  chunkCnt, boxesd, clsd, ekeysG);
  z5_sortnms   <<<dim3(Bn),              dim3(1024), 0, stream>>>(logits, anchors, ekeysG,
                                                                  chunkCnt, clist, boxesd,
                                                                  clsd, out);
}